// Round 1
// baseline (2060.508 us; speedup 1.0000x reference)
//
#include <hip/hip_runtime.h>
#include <cstddef>

namespace {
constexpr int B_ = 16, C_ = 32, N_ = 1024, L_ = 24, CO_ = 64;

constexpr size_t S_OFF = (size_t)B_*CO_*N_*L_;            // 25165824
constexpr size_t T_OFF = S_OFF + (size_t)B_*N_*N_;        // 41943040

// workspace offsets (in floats)
constexpr size_t O_RAW = 0;                               // raw_s [B][N][N]; later z1 [B][N][768]
constexpr size_t O_Z2  = O_RAW + (size_t)B_*N_*N_;        // z2 [B][N][768]
constexpr size_t O_XT2 = O_Z2  + (size_t)B_*C_*N_*L_;     // x_TAt in [B][N][C*L]
constexpr size_t O_SUP2= O_XT2 + (size_t)B_*C_*N_*L_;     // supp2 [N][N]
constexpr size_t O_F1T = O_SUP2+ (size_t)N_*N_;           // f1t [B][L][N]
constexpr size_t O_F1S = O_F1T + (size_t)B_*L_*N_;        // f1s [B][N][L]
constexpr size_t O_F2T = O_F1S + (size_t)B_*N_*L_;        // f2t [B][C][L]
constexpr size_t O_F2S = O_F2T + (size_t)B_*C_*L_;        // f2s [B][C][N]
constexpr size_t O_GT  = O_F2S + (size_t)B_*C_*N_;        // g_t [B][L][C]
constexpr size_t O_GS  = O_GT  + (size_t)B_*L_*C_;        // g_s [B][N][C]
constexpr size_t O_CM  = O_GS  + (size_t)B_*N_*C_;        // colmax [B][N]
constexpr size_t O_TWT = O_CM  + (size_t)B_*N_;           // time_w^T [192][64]
constexpr size_t O_WGT = O_TWT + 192*64;                  // gcn_w^T [96][64]
constexpr size_t O_WCT = O_WGT + 96*64;                   // conv1_w^T [32][64]
constexpr size_t O_PART= O_WCT + 32*64;                   // per-block partial sums [4096][2]
constexpr size_t O_BST = O_PART+ 4096*2;                  // [B][2]

// ---------------- stage 1: fused channel reductions over x ----------------
__global__ void k_f1(const float* __restrict__ x, const float* __restrict__ t1w,
                     const float* __restrict__ s1w, float* __restrict__ f1t,
                     float* __restrict__ f1s) {
  int idx = blockIdx.x * 256 + threadIdx.x;          // B*N*L
  int b = idx / (N_*L_); int r = idx % (N_*L_); int n = r / L_; int l = r % L_;
  const float* xp = x + ((size_t)b*C_*N_ + n)*L_ + l;
  float a1 = 0.f, a2 = 0.f;
  #pragma unroll
  for (int c = 0; c < C_; c++) {
    float v = xp[(size_t)c*N_*L_];
    a1 += v * t1w[c]; a2 += v * s1w[c];
  }
  f1t[((size_t)b*L_ + l)*N_ + n] = a1;               // [b][l][n]
  f1s[idx] = a2;                                     // [b][n][l]
}

// f2t[b,c,l] = sum_n x[b,c,n,l]*w[n] — one block per (b,c), coalesced
__global__ __launch_bounds__(768) void k_f2t(const float* __restrict__ x,
    const float* __restrict__ w, float* __restrict__ f2t) {
  int bc = blockIdx.x; int tid = threadIdx.x;        // 768 = 32 nsub x 24 l
  int nsub = tid / 24, l = tid % 24;
  const float* xp = x + (size_t)bc*N_*L_;
  float a = 0.f;
  for (int i = 0; i < 32; i++) {
    int n = nsub + i*32;
    a += xp[(size_t)n*24 + l] * w[n];
  }
  __shared__ float s[768];
  s[tid] = a; __syncthreads();
  for (int off = 16; off >= 1; off >>= 1) {
    if (nsub < off) s[tid] += s[tid + off*24];
    __syncthreads();
  }
  if (tid < 24) f2t[(size_t)bc*24 + tid] = s[tid];
}

// f2s[b,c,n] = sum_l x[b,c,n,l]*w[l]
__global__ void k_f2s(const float* __restrict__ x, const float* __restrict__ w,
                      float* __restrict__ f2s) {
  int idx = blockIdx.x * 256 + threadIdx.x;          // B*C*N
  const float* xp = x + (size_t)idx * L_;
  float a = 0.f;
  #pragma unroll
  for (int l = 0; l < L_; l++) a += xp[l] * w[l];
  f2s[idx] = a;                                      // [b][c][n]
}

// g_t[b,l,c] = sum_n f1t[b,l,n]*t_w[n,c] — block per (b,l)
__global__ __launch_bounds__(1024) void k_gt(const float* __restrict__ f1t,
    const float* __restrict__ tw, float* __restrict__ g_t) {
  int bl = blockIdx.x; int tid = threadIdx.x;        // 1024 = 32 nsub x 32 c
  int nsub = tid >> 5, c = tid & 31;
  const float* f = f1t + (size_t)bl * N_;
  float a = 0.f;
  for (int i = 0; i < 32; i++) {
    int n = nsub + (i << 5);
    a += f[n] * tw[n*32 + c];
  }
  __shared__ float s[1024];
  s[tid] = a; __syncthreads();
  for (int off = 512; off >= 32; off >>= 1) {
    if (tid < off) s[tid] += s[tid + off];
    __syncthreads();
  }
  if (tid < 32) g_t[(size_t)bl*32 + tid] = s[tid];
  (void)nsub;
}

// g_s[b,n,c] = sum_l f1s[b,n,l]*s_w[l,c]
__global__ void k_gs(const float* __restrict__ f1s, const float* __restrict__ sw,
                     float* __restrict__ g_s) {
  int idx = blockIdx.x * 256 + threadIdx.x;          // B*N*C
  int bn = idx >> 5, c = idx & 31;
  const float* f = f1s + (size_t)bn * L_;
  float a = 0.f;
  #pragma unroll
  for (int l = 0; l < L_; l++) a += f[l] * sw[l*32 + c];
  g_s[idx] = a;                                      // [b][n][c]
}

// ---------------- temporal attention (tiny, one block per b) ----------------
__global__ __launch_bounds__(576) void k_tatt(const float* __restrict__ g_t,
    const float* __restrict__ f2t, const float* __restrict__ tb,
    const float* __restrict__ tv, float* __restrict__ Tout) {
  int b = blockIdx.x; int tid = threadIdx.x;         // 576 = 24*24
  int l = tid / 24, q = tid % 24;
  __shared__ float rawS[576], logS[576], cmS[24], rmS[24], rsS[24];
  float acc = tb[tid];
  const float* g = g_t + ((size_t)b*L_ + l)*C_;
  const float* f = f2t + (size_t)b*C_*L_ + q;
  #pragma unroll
  for (int c = 0; c < C_; c++) acc += g[c] * f[(size_t)c*L_];
  rawS[tid] = 1.f / (1.f + expf(-acc));
  __syncthreads();
  float lg = 0.f;
  #pragma unroll
  for (int k = 0; k < L_; k++) lg += tv[l*L_ + k] * rawS[k*L_ + q];
  logS[tid] = lg;
  __syncthreads();
  if (l == 0) { float m = -3.4e38f; for (int mm = 0; mm < L_; mm++) m = fmaxf(m, logS[mm*L_ + q]); cmS[q] = m; }
  __syncthreads();
  float lc = lg - cmS[q];
  logS[tid] = lc;
  __syncthreads();
  if (q == 0) { float m = -3.4e38f; for (int qq = 0; qq < L_; qq++) m = fmaxf(m, logS[l*L_ + qq]); rmS[l] = m; }
  __syncthreads();
  float e = expf(lc - rmS[l]);
  logS[tid] = e;
  __syncthreads();
  if (q == 0) { float s = 0.f; for (int qq = 0; qq < L_; qq++) s += logS[l*L_ + qq]; rsS[l] = s; }
  __syncthreads();
  Tout[(size_t)b*576 + q*24 + l] = e / rsS[l];       // transposed write (ref swapaxes)
}

// ---------------- raw_s = sigmoid(g_s @ f2s + s_b) ----------------
__global__ void k_raws(const float* __restrict__ g_s, const float* __restrict__ f2s,
                       const float* __restrict__ sb, float* __restrict__ raw) {
  size_t idx = (size_t)blockIdx.x * 256 + threadIdx.x;  // B*N*N
  int b = (int)(idx >> 20); int r = (int)(idx & (size_t)(N_*N_ - 1));
  int n = r >> 10, m = r & 1023;
  const float* g = g_s + ((size_t)b*N_ + n)*C_;
  const float* f = f2s + (size_t)b*C_*N_ + m;
  float a = sb[(size_t)n*N_ + m];
  #pragma unroll
  for (int c = 0; c < C_; c++) a += g[c] * f[(size_t)c*N_];
  raw[idx] = 1.f / (1.f + expf(-a));
}

// ---------------- generic tiled f32 GEMM, 64x64 tile, 4x4 micro ----------------
template <int MODE>   // 0: plain, 1: 2*acc - I (supports^2 Chebyshev)
__global__ __launch_bounds__(256) void k_mm(const float* __restrict__ A,
    const float* __restrict__ Bm, float* __restrict__ D, int Kd,
    int ldA, int ldB, int ldD, long sA, long sB, long sD) {
  int bz = blockIdx.z;
  A += (size_t)bz * sA; Bm += (size_t)bz * sB; D += (size_t)bz * sD;
  int n0 = blockIdx.x * 64, m0 = blockIdx.y * 64;
  int tid = threadIdx.x;
  int tx = tid & 15, ty = tid >> 4;
  __shared__ __align__(16) float As[16][68], Bs[16][68];
  float acc[4][4] = {};
  int arow = tid >> 2, akq = (tid & 3) * 4;
  int bkk = tid >> 4, bcol = (tid & 15) * 4;
  const float* Ap = A + (size_t)(m0 + arow)*ldA + akq;
  const float* Bp = Bm + (size_t)bkk*ldB + n0 + bcol;
  for (int k0 = 0; k0 < Kd; k0 += 16) {
    float4 a4 = *(const float4*)(Ap + k0);
    float4 b4 = *(const float4*)(Bp + (size_t)k0 * ldB);
    __syncthreads();
    As[akq+0][arow] = a4.x; As[akq+1][arow] = a4.y;
    As[akq+2][arow] = a4.z; As[akq+3][arow] = a4.w;
    *(float4*)&Bs[bkk][bcol] = b4;
    __syncthreads();
    #pragma unroll
    for (int kk = 0; kk < 16; kk++) {
      float av[4], bv[4];
      *(float4*)av = *(const float4*)&As[kk][ty*4];
      *(float4*)bv = *(const float4*)&Bs[kk][tx*4];
      #pragma unroll
      for (int i = 0; i < 4; i++)
        #pragma unroll
        for (int j = 0; j < 4; j++) acc[i][j] += av[i] * bv[j];
    }
  }
  #pragma unroll
  for (int i = 0; i < 4; i++) {
    int rr = m0 + ty*4 + i;
    float ov[4];
    #pragma unroll
    for (int j = 0; j < 4; j++) {
      float v = acc[i][j];
      if (MODE == 1) v = 2.f*v - ((rr == n0 + tx*4 + j) ? 1.f : 0.f);
      ov[j] = v;
    }
    *(float4*)&D[(size_t)rr*ldD + n0 + tx*4] = *(float4*)ov;
  }
}

// ---------------- column max over m (axis=1) ----------------
__global__ void k_colmax(const float* __restrict__ logit, float* __restrict__ cm) {
  int idx = blockIdx.x * 256 + threadIdx.x;          // B*N
  int b = idx >> 10, q = idx & 1023;
  const float* base = logit + (size_t)b*N_*N_ + q;
  float m = -3.4e38f;
  #pragma unroll 8
  for (int mm = 0; mm < N_; mm++) m = fmaxf(m, base[(size_t)mm * N_]);
  cm[idx] = m;
}

// ---------------- in-place row softmax of (logits - colmax) ----------------
__global__ __launch_bounds__(256) void k_softmax(float* __restrict__ S,
                                                 const float* __restrict__ cm) {
  int bm = blockIdx.x; int tid = threadIdx.x;
  int b = bm >> 10;
  float* row = S + (size_t)bm * N_;
  const float* cmb = cm + (size_t)b * N_;
  float v[4]; float mx = -3.4e38f;
  #pragma unroll
  for (int j = 0; j < 4; j++) { int q = tid + j*256; v[j] = row[q] - cmb[q]; mx = fmaxf(mx, v[j]); }
  #pragma unroll
  for (int off = 32; off; off >>= 1) mx = fmaxf(mx, __shfl_down(mx, off));
  __shared__ float sm[4], ss[4];
  if ((tid & 63) == 0) sm[tid >> 6] = mx;
  __syncthreads();
  mx = fmaxf(fmaxf(sm[0], sm[1]), fmaxf(sm[2], sm[3]));
  float e[4]; float s = 0.f;
  #pragma unroll
  for (int j = 0; j < 4; j++) { e[j] = expf(v[j] - mx); s += e[j]; }
  #pragma unroll
  for (int off = 32; off; off >>= 1) s += __shfl_down(s, off);
  if ((tid & 63) == 0) ss[tid >> 6] = s;
  __syncthreads();
  float inv = 1.f / (ss[0] + ss[1] + ss[2] + ss[3]);
  #pragma unroll
  for (int j = 0; j < 4; j++) row[tid + j*256] = e[j] * inv;
}

// ---------------- x_TAt (relayout to [b][n][c*L]) ----------------
__global__ __launch_bounds__(768) void k_xtat(const float* __restrict__ x,
    const float* __restrict__ Tout, float* __restrict__ xT2) {
  int bn = blockIdx.x; int b = bn >> 10, n = bn & 1023;
  __shared__ float xrow[768], Tl[576];
  int tid = threadIdx.x;
  int c = tid / 24, q = tid % 24;
  xrow[tid] = x[(((size_t)b*C_ + c)*N_ + n)*L_ + q];
  if (tid < 576) Tl[tid] = Tout[(size_t)b*576 + tid];
  __syncthreads();
  float acc = 0.f;
  #pragma unroll
  for (int ll = 0; ll < 24; ll++) acc += xrow[c*24 + ll] * Tl[ll*24 + q];
  xT2[(size_t)bn*768 + tid] = acc;
}

// ---------------- Chebyshev dual GEMM: z_k = (S . T_k)^T-contraction @ x_TAt ----------------
__global__ __launch_bounds__(256) void k_cheb(const float* __restrict__ S,
    const float* __restrict__ sup, const float* __restrict__ sup2,
    const float* __restrict__ X, float* __restrict__ z1, float* __restrict__ z2) {
  int b = blockIdx.z;
  int jt0 = blockIdx.x * 64, q0 = blockIdx.y * 64;
  int tid = threadIdx.x;
  int tx = tid & 15, ty = tid >> 4;
  __shared__ __align__(16) float A1s[16][68], A2s[16][68], Bs[16][68];
  float acc1[4][4] = {}, acc2[4][4] = {};
  int arow = tid >> 2, akq = (tid & 3) * 4;
  int bkk = tid >> 4, bcol = (tid & 15) * 4;
  const float* Sp  = S + ((size_t)b*N_ + q0 + arow)*N_ + akq;
  const float* P1p = sup  + (size_t)(q0 + arow)*N_ + akq;
  const float* P2p = sup2 + (size_t)(q0 + arow)*N_ + akq;
  const float* Xp  = X + ((size_t)b*N_ + bkk)*768 + jt0 + bcol;
  for (int k0 = 0; k0 < N_; k0 += 16) {
    float4 s4  = *(const float4*)(Sp + k0);
    float4 p14 = *(const float4*)(P1p + k0);
    float4 p24 = *(const float4*)(P2p + k0);
    float4 x4  = *(const float4*)(Xp + (size_t)k0 * 768);
    __syncthreads();
    A1s[akq+0][arow] = s4.x*p14.x; A1s[akq+1][arow] = s4.y*p14.y;
    A1s[akq+2][arow] = s4.z*p14.z; A1s[akq+3][arow] = s4.w*p14.w;
    A2s[akq+0][arow] = s4.x*p24.x; A2s[akq+1][arow] = s4.y*p24.y;
    A2s[akq+2][arow] = s4.z*p24.z; A2s[akq+3][arow] = s4.w*p24.w;
    *(float4*)&Bs[bkk][bcol] = x4;
    __syncthreads();
    #pragma unroll
    for (int kk = 0; kk < 16; kk++) {
      float a1[4], a2[4], bv[4];
      *(float4*)a1 = *(const float4*)&A1s[kk][ty*4];
      *(float4*)a2 = *(const float4*)&A2s[kk][ty*4];
      *(float4*)bv = *(const float4*)&Bs[kk][tx*4];
      #pragma unroll
      for (int i = 0; i < 4; i++)
        #pragma unroll
        for (int j = 0; j < 4; j++) {
          acc1[i][j] += a1[i] * bv[j];
          acc2[i][j] += a2[i] * bv[j];
        }
    }
  }
  #pragma unroll
  for (int i = 0; i < 4; i++) {
    size_t ro = ((size_t)b*N_ + q0 + ty*4 + i)*768 + jt0 + tx*4;
    *(float4*)&z1[ro] = *(float4*)acc1[i];
    *(float4*)&z2[ro] = *(float4*)acc2[i];
  }
}

// ---------------- weight repack (transposed copies for vec4 broadcast) ----------------
__global__ void k_wrepack(const float* __restrict__ gcn_w, const float* __restrict__ conv1_w,
                          const float* __restrict__ time_w, float* __restrict__ wGT,
                          float* __restrict__ wCT, float* __restrict__ twT) {
  int idx = blockIdx.x * 256 + threadIdx.x;
  if (idx < 96*64)  { int f = idx >> 6, o = idx & 63; wGT[idx] = gcn_w[o*96 + f]; }
  if (idx < 32*64)  { int c = idx >> 6, o = idx & 63; wCT[idx] = conv1_w[o*32 + c]; }
  if (idx < 192*64) { int f = idx >> 6, o = idx & 63; twT[idx] = time_w[o*192 + f]; }
}

// ---------------- fused gcn-conv + relu + time-conv + x_input + relu + LN-stats ----------------
constexpr int QB = 4;
constexpr int XTS = 776;            // padded LDS stride for xt/z1/z2 panels
constexpr int GST = 64*26 + 8;      // padded per-q stride of gcn LDS (l padded to 26)
__global__ __launch_bounds__(384) void k_gcn_time(
    const float* __restrict__ xT2, const float* __restrict__ z1, const float* __restrict__ z2,
    const float* __restrict__ S, const float* __restrict__ x,
    const float* __restrict__ wGT, const float* __restrict__ wCT, const float* __restrict__ twT,
    const float* __restrict__ gcn_b, const float* __restrict__ time_b,
    const float* __restrict__ conv1_b, float* __restrict__ out, float* __restrict__ partials) {
  int blk = blockIdx.x;             // 4096 = B * 256
  int b = blk >> 8;
  int q0 = (blk & 255) * QB;
  int tid = threadIdx.x;
  __shared__ __align__(16) float xtS[QB*XTS], z1S[QB*XTS], z2S[QB*XTS];
  __shared__ __align__(16) float gS[QB*GST];
  __shared__ float sdS[QB];
  __shared__ float red[12];
  // phase 1: stage panels
  for (int t = tid; t < QB*768; t += 384) {
    int qi = t / 768, j = t % 768;
    size_t src = ((size_t)(b*N_ + q0 + qi))*768 + j;
    xtS[qi*XTS + j] = xT2[src];
    z1S[qi*XTS + j] = z1[src];
    z2S[qi*XTS + j] = z2[src];
  }
  if (tid < QB) { int q = q0 + tid; sdS[tid] = S[((size_t)b*N_ + q)*N_ + q]; }
  for (int t = tid; t < QB*64; t += 384) {
    int qi = t >> 6, i = t & 63;
    gS[qi*GST + i*26 + 0] = 0.f; gS[qi*GST + i*26 + 25] = 0.f;
  }
  __syncthreads();
  int og = tid / 24; int r = tid % 24; int qi = r / 6; int lg = r % 6;
  int o0 = og*4, l0 = lg*4;
  int q = q0 + qi;
  // phase 2: gcn = W0*(sd*xT) + W1*z1 + W2*z2 ; relu
  float acc[4][4] = {};
  float sd = sdS[qi];
  const float* xtp = &xtS[qi*XTS];
  const float* z1p = &z1S[qi*XTS];
  const float* z2p = &z2S[qi*XTS];
  for (int c = 0; c < C_; c++) {
    float b0[4], b1[4], b2[4], a0[4], a1[4], a2[4];
    *(float4*)b0 = *(const float4*)(xtp + c*24 + l0);
    *(float4*)b1 = *(const float4*)(z1p + c*24 + l0);
    *(float4*)b2 = *(const float4*)(z2p + c*24 + l0);
    *(float4*)a0 = *(const float4*)(wGT + (c*3+0)*64 + o0);
    *(float4*)a1 = *(const float4*)(wGT + (c*3+1)*64 + o0);
    *(float4*)a2 = *(const float4*)(wGT + (c*3+2)*64 + o0);
    float sb0[4] = {sd*b0[0], sd*b0[1], sd*b0[2], sd*b0[3]};
    #pragma unroll
    for (int i = 0; i < 4; i++)
      #pragma unroll
      for (int j = 0; j < 4; j++)
        acc[i][j] += a0[i]*sb0[j] + a1[i]*b1[j] + a2[i]*b2[j];
  }
  #pragma unroll
  for (int i = 0; i < 4; i++) {
    float gb = gcn_b[o0 + i];
    #pragma unroll
    for (int j = 0; j < 4; j++)
      gS[qi*GST + (o0+i)*26 + 1 + l0 + j] = fmaxf(acc[i][j] + gb, 0.f);
  }
  __syncthreads();
  // phase 3: time conv (padded along l) + x_input + relu
  float acc2[4][4] = {};
  const float* gp = &gS[qi*GST];
  for (int i2 = 0; i2 < CO_; i2++) {
    float gv[6];
    #pragma unroll
    for (int u = 0; u < 6; u++) gv[u] = gp[i2*26 + l0 + u];
    #pragma unroll
    for (int t = 0; t < 3; t++) {
      float a[4];
      *(float4*)a = *(const float4*)(twT + (i2*3+t)*64 + o0);
      #pragma unroll
      for (int i = 0; i < 4; i++)
        #pragma unroll
        for (int j = 0; j < 4; j++) acc2[i][j] += a[i] * gv[t + j];
    }
  }
  float accx[4][4] = {};
  const float* xb = x + ((size_t)b*C_*N_ + q)*L_ + l0;
  for (int c = 0; c < C_; c++) {
    float xv[4], a[4];
    *(float4*)xv = *(const float4*)(xb + (size_t)c*N_*L_);
    *(float4*)a  = *(const float4*)(wCT + c*64 + o0);
    #pragma unroll
    for (int i = 0; i < 4; i++)
      #pragma unroll
      for (int j = 0; j < 4; j++) accx[i][j] += a[i] * xv[j];
  }
  float s1 = 0.f, s2 = 0.f;
  #pragma unroll
  for (int i = 0; i < 4; i++) {
    float tb = time_b[o0 + i], cb = conv1_b[o0 + i];
    float ov[4];
    #pragma unroll
    for (int j = 0; j < 4; j++) {
      float pre = fmaxf(acc2[i][j] + tb + accx[i][j] + cb, 0.f);
      s1 += pre; s2 += pre * pre; ov[j] = pre;
    }
    *(float4*)&out[(((size_t)b*CO_ + o0 + i)*N_ + q)*L_ + l0] = *(float4*)ov;
  }
  // deterministic block reduction of (sum, sumsq)
  #pragma unroll
  for (int off = 32; off; off >>= 1) { s1 += __shfl_down(s1, off); s2 += __shfl_down(s2, off); }
  if ((tid & 63) == 0) { red[(tid >> 6)*2] = s1; red[(tid >> 6)*2 + 1] = s2; }
  __syncthreads();
  if (tid == 0) {
    float t1 = 0.f, t2 = 0.f;
    for (int w = 0; w < 6; w++) { t1 += red[w*2]; t2 += red[w*2+1]; }
    partials[blk*2] = t1; partials[blk*2 + 1] = t2;
  }
}

__global__ __launch_bounds__(256) void k_bstats(const float* __restrict__ partials,
                                                float* __restrict__ bstats) {
  int b = blockIdx.x; int tid = threadIdx.x;
  __shared__ float r1[256], r2[256];
  r1[tid] = partials[(b*256 + tid)*2];
  r2[tid] = partials[(b*256 + tid)*2 + 1];
  __syncthreads();
  for (int off = 128; off; off >>= 1) {
    if (tid < off) { r1[tid] += r1[tid + off]; r2[tid] += r2[tid + off]; }
    __syncthreads();
  }
  if (tid == 0) { bstats[b*2] = r1[0]; bstats[b*2 + 1] = r2[0]; }
}

__global__ void k_ln(float* __restrict__ out, const float* __restrict__ bstats,
                     const float* __restrict__ lnw, const float* __restrict__ lnb) {
  size_t idx = (size_t)blockIdx.x * 256 + threadIdx.x;   // B*CO*N*L
  constexpr size_t PER = (size_t)CO_*N_*L_;
  int b = (int)(idx / PER); size_t r = idx % PER;
  float cnt = (float)PER;
  float mu = bstats[b*2] / cnt;
  float var = bstats[b*2 + 1] / cnt - mu*mu;
  float inv = rsqrtf(var + 1e-5f);
  out[idx] = (out[idx] - mu) * inv * lnw[r] + lnb[r];
}
} // namespace

extern "C" void kernel_launch(void* const* d_in, const int* in_sizes, int n_in,
                              void* d_out, int out_size, void* d_ws, size_t ws_size,
                              hipStream_t stream) {
  const float* x        = (const float*)d_in[0];
  const float* supports = (const float*)d_in[1];
  const float* conv1_w  = (const float*)d_in[2];
  const float* conv1_b  = (const float*)d_in[3];
  const float* t1w      = (const float*)d_in[4];
  const float* t2w      = (const float*)d_in[5];
  const float* t_w      = (const float*)d_in[6];
  const float* t_b      = (const float*)d_in[7];
  const float* t_v      = (const float*)d_in[8];
  const float* s1w      = (const float*)d_in[9];
  const float* s2w      = (const float*)d_in[10];
  const float* s_w      = (const float*)d_in[11];
  const float* s_b      = (const float*)d_in[12];
  const float* s_v      = (const float*)d_in[13];
  const float* gcn_w    = (const float*)d_in[14];
  const float* gcn_b    = (const float*)d_in[15];
  const float* time_w   = (const float*)d_in[16];
  const float* time_b   = (const float*)d_in[17];
  const float* ln_w     = (const float*)d_in[18];
  const float* ln_b     = (const float*)d_in[19];

  float* out  = (float*)d_out;
  float* Sout = out + S_OFF;      // [B][N][N]: holds logits, then S_coef in place
  float* Tout = out + T_OFF;      // [B][L][L] (already transposed)
  float* ws   = (float*)d_ws;

  float* raw_s = ws + O_RAW;
  float* zz1   = ws + O_RAW;      // aliases raw_s (dead after logits GEMM)
  float* zz2   = ws + O_Z2;
  float* xT2   = ws + O_XT2;
  float* sup2  = ws + O_SUP2;
  float* f1t   = ws + O_F1T;
  float* f1s   = ws + O_F1S;
  float* f2t   = ws + O_F2T;
  float* f2s   = ws + O_F2S;
  float* g_t   = ws + O_GT;
  float* g_s   = ws + O_GS;
  float* cm    = ws + O_CM;
  float* twT   = ws + O_TWT;
  float* wGT   = ws + O_WGT;
  float* wCT   = ws + O_WCT;
  float* part  = ws + O_PART;
  float* bst   = ws + O_BST;

  constexpr long NN = (long)N_*N_;

  k_f1<<<1536, 256, 0, stream>>>(x, t1w, s1w, f1t, f1s);
  k_f2t<<<B_*C_, 768, 0, stream>>>(x, t2w, f2t);
  k_f2s<<<2048, 256, 0, stream>>>(x, s2w, f2s);
  k_gt<<<B_*L_, 1024, 0, stream>>>(f1t, t_w, g_t);
  k_gs<<<2048, 256, 0, stream>>>(f1s, s_w, g_s);
  k_tatt<<<B_, 576, 0, stream>>>(g_t, f2t, t_b, t_v, Tout);
  k_raws<<<65536, 256, 0, stream>>>(g_s, f2s, s_b, raw_s);
  // supports @ supports -> T2 Chebyshev basis
  k_mm<1><<<dim3(16, 16, 1), 256, 0, stream>>>(supports, supports, sup2,
                                               N_, N_, N_, N_, 0, 0, 0);
  // logits = s_v @ raw_s  (into d_out S region)
  k_mm<0><<<dim3(16, 16, B_), 256, 0, stream>>>(s_v, raw_s, Sout,
                                                N_, N_, N_, N_, 0, NN, NN);
  k_colmax<<<64, 256, 0, stream>>>(Sout, cm);
  k_softmax<<<B_*N_, 256, 0, stream>>>(Sout, cm);
  k_xtat<<<B_*N_, 768, 0, stream>>>(x, Tout, xT2);
  k_cheb<<<dim3(12, 16, B_), 256, 0, stream>>>(Sout, supports, sup2, xT2, zz1, zz2);
  k_wrepack<<<48, 256, 0, stream>>>(gcn_w, conv1_w, time_w, wGT, wCT, twT);
  k_gcn_time<<<4096, 384, 0, stream>>>(xT2, zz1, zz2, Sout, x, wGT, wCT, twT,
                                       gcn_b, time_b, conv1_b, out, part);
  k_bstats<<<B_, 256, 0, stream>>>(part, bst);
  k_ln<<<98304, 256, 0, stream>>>(out, bst, ln_w, ln_b);
}

// Round 2
// 1104.545 us; speedup vs baseline: 1.8655x; 1.8655x over previous
//
#include <hip/hip_runtime.h>
#include <cstddef>

namespace {
constexpr int B_ = 16, C_ = 32, N_ = 1024, L_ = 24, CO_ = 64;

constexpr size_t S_OFF = (size_t)B_*CO_*N_*L_;            // 25165824 floats
constexpr size_t T_OFF = S_OFF + (size_t)B_*N_*N_;        // 41943040

// workspace offsets (in floats) — identical footprint to the passing round
constexpr size_t O_RAW = 0;                               // rawp bf16 [B][N*N]; later z1 f32 [B][N][768]
constexpr size_t O_Z2  = O_RAW + (size_t)B_*N_*N_;        // z2 [B][N][768]
constexpr size_t O_XT2 = O_Z2  + (size_t)B_*C_*N_*L_;     // x_TAt f32 [B][N][C*L]
constexpr size_t O_SUP2= O_XT2 + (size_t)B_*C_*N_*L_;     // supp2 [N][N]
constexpr size_t O_F1T = O_SUP2+ (size_t)N_*N_;           // f1t [B][L][N]
constexpr size_t O_F1S = O_F1T + (size_t)B_*L_*N_;        // f1s [B][N][L]
constexpr size_t O_F2T = O_F1S + (size_t)B_*N_*L_;        // f2t [B][C][L]
constexpr size_t O_F2S = O_F2T + (size_t)B_*C_*L_;        // f2s [B][C][N]
constexpr size_t O_GT  = O_F2S + (size_t)B_*C_*N_;        // g_t [B][L][C]
constexpr size_t O_GS  = O_GT  + (size_t)B_*L_*C_;        // g_s [B][N][C]
constexpr size_t O_CM  = O_GS  + (size_t)B_*N_*C_;        // colmax [B][N]
constexpr size_t O_TWT = O_CM  + (size_t)B_*N_;           // time_w^T [192][64]
constexpr size_t O_WGT = O_TWT + 192*64;                  // gcn_w^T [96][64]
constexpr size_t O_WCT = O_WGT + 96*64;                   // conv1_w^T [32][64]
constexpr size_t O_PART= O_WCT + 32*64;                   // per-block partials [4096][2]
constexpr size_t O_BST = O_PART+ 4096*2;                  // [B][2]

// d_out scratch offsets (in u16 units) — region [0, S_OFF floats) is only
// written by k_gcn_time at the very end, so earlier kernels may use it.
constexpr size_t OS_A1 = 0;                               // A1 packed bf16 [B][N*N]
constexpr size_t OS_A2 = OS_A1 + (size_t)B_*N_*N_;        // A2 packed bf16
constexpr size_t OS_XP = OS_A2 + (size_t)B_*N_*N_;        // X packed bf16 [B][1024*768]
constexpr size_t OS_SV = OS_XP + (size_t)B_*N_*768;       // s_v packed bf16 [N*N]
// ends at 47.2M u16 = 94.4MB < 100.7MB (S_OFF*4) -- OK

typedef unsigned short u16;
typedef __attribute__((ext_vector_type(8))) short short8v;
typedef __attribute__((ext_vector_type(4))) float f32x4;

__device__ __forceinline__ u16 f2bf(float x) {
  unsigned u = __builtin_bit_cast(unsigned, x);
  return (u16)((u + 0x7fffu + ((u >> 16) & 1u)) >> 16);
}

__device__ __forceinline__ void gl_lds16(const void* g, void* l) {
  __builtin_amdgcn_global_load_lds(
      (const __attribute__((address_space(1))) unsigned int*)g,
      (__attribute__((address_space(3))) unsigned int*)l, 16, 0, 0);
}

// ---------------- stage 1: fused channel reductions over x ----------------
__global__ void k_f1(const float* __restrict__ x, const float* __restrict__ t1w,
                     const float* __restrict__ s1w, float* __restrict__ f1t,
                     float* __restrict__ f1s) {
  int idx = blockIdx.x * 256 + threadIdx.x;          // B*N*L
  int b = idx / (N_*L_); int r = idx % (N_*L_); int n = r / L_; int l = r % L_;
  const float* xp = x + ((size_t)b*C_*N_ + n)*L_ + l;
  float a1 = 0.f, a2 = 0.f;
  #pragma unroll
  for (int c = 0; c < C_; c++) {
    float v = xp[(size_t)c*N_*L_];
    a1 += v * t1w[c]; a2 += v * s1w[c];
  }
  f1t[((size_t)b*L_ + l)*N_ + n] = a1;               // [b][l][n]
  f1s[idx] = a2;                                     // [b][n][l]
}

__global__ __launch_bounds__(768) void k_f2t(const float* __restrict__ x,
    const float* __restrict__ w, float* __restrict__ f2t) {
  int bc = blockIdx.x; int tid = threadIdx.x;        // 768 = 32 nsub x 24 l
  int nsub = tid / 24, l = tid % 24;
  const float* xp = x + (size_t)bc*N_*L_;
  float a = 0.f;
  for (int i = 0; i < 32; i++) {
    int n = nsub + i*32;
    a += xp[(size_t)n*24 + l] * w[n];
  }
  __shared__ float s[768];
  s[tid] = a; __syncthreads();
  for (int off = 16; off >= 1; off >>= 1) {
    if (nsub < off) s[tid] += s[tid + off*24];
    __syncthreads();
  }
  if (tid < 24) f2t[(size_t)bc*24 + tid] = s[tid];
}

__global__ void k_f2s(const float* __restrict__ x, const float* __restrict__ w,
                      float* __restrict__ f2s) {
  int idx = blockIdx.x * 256 + threadIdx.x;          // B*C*N
  const float* xp = x + (size_t)idx * L_;
  float a = 0.f;
  #pragma unroll
  for (int l = 0; l < L_; l++) a += xp[l] * w[l];
  f2s[idx] = a;                                      // [b][c][n]
}

__global__ __launch_bounds__(1024) void k_gt(const float* __restrict__ f1t,
    const float* __restrict__ tw, float* __restrict__ g_t) {
  int bl = blockIdx.x; int tid = threadIdx.x;        // 1024 = 32 nsub x 32 c
  int nsub = tid >> 5, c = tid & 31;
  const float* f = f1t + (size_t)bl * N_;
  float a = 0.f;
  for (int i = 0; i < 32; i++) {
    int n = nsub + (i << 5);
    a += f[n] * tw[n*32 + c];
  }
  __shared__ float s[1024];
  s[tid] = a; __syncthreads();
  for (int off = 512; off >= 32; off >>= 1) {
    if (tid < off) s[tid] += s[tid + off];
    __syncthreads();
  }
  if (tid < 32) g_t[(size_t)bl*32 + tid] = s[tid];
  (void)nsub;
}

__global__ void k_gs(const float* __restrict__ f1s, const float* __restrict__ sw,
                     float* __restrict__ g_s) {
  int idx = blockIdx.x * 256 + threadIdx.x;          // B*N*C
  int bn = idx >> 5, c = idx & 31;
  const float* f = f1s + (size_t)bn * L_;
  float a = 0.f;
  #pragma unroll
  for (int l = 0; l < L_; l++) a += f[l] * sw[l*32 + c];
  g_s[idx] = a;                                      // [b][n][c]
}

// ---------------- temporal attention ----------------
__global__ __launch_bounds__(576) void k_tatt(const float* __restrict__ g_t,
    const float* __restrict__ f2t, const float* __restrict__ tb,
    const float* __restrict__ tv, float* __restrict__ Tout) {
  int b = blockIdx.x; int tid = threadIdx.x;         // 576 = 24*24
  int l = tid / 24, q = tid % 24;
  __shared__ float rawS[576], logS[576], cmS[24], rmS[24], rsS[24];
  float acc = tb[tid];
  const float* g = g_t + ((size_t)b*L_ + l)*C_;
  const float* f = f2t + (size_t)b*C_*L_ + q;
  #pragma unroll
  for (int c = 0; c < C_; c++) acc += g[c] * f[(size_t)c*L_];
  rawS[tid] = 1.f / (1.f + expf(-acc));
  __syncthreads();
  float lg = 0.f;
  #pragma unroll
  for (int k = 0; k < L_; k++) lg += tv[l*L_ + k] * rawS[k*L_ + q];
  logS[tid] = lg;
  __syncthreads();
  if (l == 0) { float m = -3.4e38f; for (int mm = 0; mm < L_; mm++) m = fmaxf(m, logS[mm*L_ + q]); cmS[q] = m; }
  __syncthreads();
  float lc = lg - cmS[q];
  logS[tid] = lc;
  __syncthreads();
  if (q == 0) { float m = -3.4e38f; for (int qq = 0; qq < L_; qq++) m = fmaxf(m, logS[l*L_ + qq]); rmS[l] = m; }
  __syncthreads();
  float e = expf(lc - rmS[l]);
  logS[tid] = e;
  __syncthreads();
  if (q == 0) { float s = 0.f; for (int qq = 0; qq < L_; qq++) s += logS[l*L_ + qq]; rsS[l] = s; }
  __syncthreads();
  Tout[(size_t)b*576 + q*24 + l] = e / rsS[l];       // transposed (ref swapaxes)
}

// ---------------- raw_s sigmoid -> packed-B bf16 directly ----------------
// B-operand frag layout (32k x 16n): lane l holds col=nb*16+(l&15),
// k = kb*32 + 8*(l>>4) + j, j=0..7 -> each thread emits one 16B lane-chunk.
__global__ void k_raws_pack(const float* __restrict__ g_s, const float* __restrict__ f2s,
                            const float* __restrict__ sb, u16* __restrict__ rawp) {
  int t = blockIdx.x * 256 + threadIdx.x;            // B * 131072
  int b = t >> 17, tt = t & 131071;
  int fi = tt >> 6, l = tt & 63;
  int kb = fi >> 6, nb = fi & 63;
  int m  = (nb << 4) + (l & 15);
  int n0 = (kb << 5) + ((l >> 4) << 3);
  const float* f = f2s + ((size_t)b*C_*N_) + m;
  float fv[C_];
  #pragma unroll
  for (int c = 0; c < C_; c++) fv[c] = f[(size_t)c << 10];
  const float* g = g_s + (((size_t)b << 10) + n0) * C_;
  u16* d = rawp + ((size_t)b << 20) + ((size_t)fi << 9) + (l << 3);
  #pragma unroll
  for (int j = 0; j < 8; j++) {
    float a = sb[(size_t)(n0 + j)*N_ + m];
    const float* gr = g + j*C_;
    #pragma unroll
    for (int c = 0; c < C_; c++) a += gr[c] * fv[c];
    d[j] = f2bf(1.f / (1.f + expf(-a)));
  }
}

// ---------------- pack s_v into A-operand bf16 layout ----------------
// A frag (16m x 32k): lane l holds row=mg*16+(l&15), k=kg*32+8*(l>>4)+j
__global__ void k_pack_sv(const float* __restrict__ sv, u16* __restrict__ svp) {
  int t = blockIdx.x * 256 + threadIdx.x;            // 131072
  int fi = t >> 6, l = t & 63;
  int mg = fi >> 5, kg = fi & 31;
  int row = (mg << 4) + (l & 15);
  int k   = (kg << 5) + ((l >> 4) << 3);
  const float* s = sv + (size_t)row*N_ + k;
  u16* d = svp + ((size_t)fi << 9) + (l << 3);
  #pragma unroll
  for (int j = 0; j < 8; j++) d[j] = f2bf(s[j]);
}

// ---------------- pack A1=S.*sup, A2=S.*sup2 (per batch) ----------------
__global__ void k_pack_cheb(const float* __restrict__ S, const float* __restrict__ sup,
                            const float* __restrict__ sup2, u16* __restrict__ A1p,
                            u16* __restrict__ A2p) {
  int t = blockIdx.x * 256 + threadIdx.x;            // B * 131072
  int b = t >> 17, tt = t & 131071;
  int fi = tt >> 6, l = tt & 63;
  int mg = fi >> 5, kg = fi & 31;
  int row = (mg << 4) + (l & 15);
  int k   = (kg << 5) + ((l >> 4) << 3);
  const float* sp = S + ((size_t)b << 20) + (size_t)row*N_ + k;
  const float* p1 = sup  + (size_t)row*N_ + k;
  const float* p2 = sup2 + (size_t)row*N_ + k;
  size_t off = ((size_t)b << 20) + ((size_t)fi << 9) + (l << 3);
  #pragma unroll
  for (int j = 0; j < 8; j++) {
    float s = sp[j];
    A1p[off + j] = f2bf(s * p1[j]);
    A2p[off + j] = f2bf(s * p2[j]);
  }
}

// ---------------- pack x_TAt [b][k=1024][768] into B-operand bf16 ----------------
__global__ void k_pack_x(const float* __restrict__ xT2, u16* __restrict__ Xp) {
  int t = blockIdx.x * 256 + threadIdx.x;            // B * 98304
  int b = t / 98304, tt = t % 98304;
  int fi = tt >> 6, l = tt & 63;
  int kb = fi / 48, nb = fi % 48;
  int col = (nb << 4) + (l & 15);
  int kr  = (kb << 5) + ((l >> 4) << 3);
  const float* xs = xT2 + ((size_t)b*N_ + kr)*768 + col;
  u16* d = Xp + (size_t)b*786432 + ((size_t)fi << 9) + (l << 3);
  #pragma unroll
  for (int j = 0; j < 8; j++) d[j] = f2bf(xs[(size_t)j*768]);
}

// ---------------- bf16 MFMA GEMM (packed-fragment operands) ----------------
// BM=BN=128, BK=64, 256 threads (4 waves, 2x2), each wave 64x64 out.
// DUAL=1: two A matrices sharing the B tile (Chebyshev z1,z2).
template <int DUAL>
__global__ __launch_bounds__(256) void k_mfma(
    const u16* __restrict__ Ap, const u16* __restrict__ A2p,
    const u16* __restrict__ Bp, float* __restrict__ D1, float* __restrict__ D2,
    int Kd, int Ncols, long sA, long sB, long sD) {
  int b = blockIdx.z;
  const u16* A1 = Ap + (size_t)b * sA;
  const u16* A2 = DUAL ? (A2p + (size_t)b * sA) : nullptr;
  const u16* Bm = Bp + (size_t)b * sB;
  int mg0 = blockIdx.y * 8;                 // 16-row groups
  int ng0 = blockIdx.x * 8;                 // 16-col groups
  int Kg = Kd >> 5;                         // 32-k groups
  int Ng = Ncols >> 4;
  int tid = threadIdx.x;
  int w = tid >> 6, lane = tid & 63;
  int wr = w >> 1, wc = w & 1;
  __shared__ __align__(16) u16 smem[(DUAL ? 3 : 2) * 8192];
  u16* As  = smem;
  u16* A2s = smem + 8192;
  u16* Bs  = smem + (DUAL ? 16384 : 8192);
  f32x4 acc1[4][4] = {};
  f32x4 acc2[4][4] = {};

  for (int k0 = 0; k0 < Kg; k0 += 2) {
    __syncthreads();
    #pragma unroll
    for (int i = 0; i < 4; i++) {
      int f = w + 4*i;                      // 16 frags, 4 per wave
      int r = f >> 1, c = f & 1;
      size_t goff = (((size_t)(mg0 + r)) * Kg + (k0 + c)) * 512 + (lane << 3);
      gl_lds16(A1 + goff, &As[f * 512]);
      if (DUAL) gl_lds16(A2 + goff, &A2s[f * 512]);
      int cb = f >> 3, tn = f & 7;
      size_t boff = (((size_t)(k0 + cb)) * Ng + (ng0 + tn)) * 512 + (lane << 3);
      gl_lds16(Bm + boff, &Bs[f * 512]);
    }
    __syncthreads();
    #pragma unroll
    for (int kk = 0; kk < 2; kk++) {
      short8v bq[4], av[4], av2[4];
      #pragma unroll
      for (int j = 0; j < 4; j++)
        bq[j] = *(const short8v*)&Bs[(kk*8 + wc*4 + j)*512 + (lane << 3)];
      #pragma unroll
      for (int i = 0; i < 4; i++) {
        av[i] = *(const short8v*)&As[((wr*4 + i)*2 + kk)*512 + (lane << 3)];
        if (DUAL)
          av2[i] = *(const short8v*)&A2s[((wr*4 + i)*2 + kk)*512 + (lane << 3)];
      }
      #pragma unroll
      for (int i = 0; i < 4; i++)
        #pragma unroll
        for (int j = 0; j < 4; j++) {
          acc1[i][j] = __builtin_amdgcn_mfma_f32_16x16x32_bf16(av[i], bq[j], acc1[i][j], 0, 0, 0);
          if (DUAL)
            acc2[i][j] = __builtin_amdgcn_mfma_f32_16x16x32_bf16(av2[i], bq[j], acc2[i][j], 0, 0, 0);
        }
    }
  }
  float* d1 = D1 + (size_t)b * sD;
  float* d2 = DUAL ? (D2 + (size_t)b * sD) : nullptr;
  #pragma unroll
  for (int i = 0; i < 4; i++) {
    int row = (mg0 + wr*4 + i)*16 + ((lane >> 4) << 2);
    #pragma unroll
    for (int j = 0; j < 4; j++) {
      int col = (ng0 + wc*4 + j)*16 + (lane & 15);
      #pragma unroll
      for (int r = 0; r < 4; r++) {
        d1[(size_t)(row + r)*Ncols + col] = acc1[i][j][r];
        if (DUAL) d2[(size_t)(row + r)*Ncols + col] = acc2[i][j][r];
      }
    }
  }
}

// ---------------- f32 tiled GEMM (kept for supports@supports) ----------------
template <int MODE>   // 1: 2*acc - I
__global__ __launch_bounds__(256) void k_mm(const float* __restrict__ A,
    const float* __restrict__ Bm, float* __restrict__ D, int Kd,
    int ldA, int ldB, int ldD, long sA, long sB, long sD) {
  int bz = blockIdx.z;
  A += (size_t)bz * sA; Bm += (size_t)bz * sB; D += (size_t)bz * sD;
  int n0 = blockIdx.x * 64, m0 = blockIdx.y * 64;
  int tid = threadIdx.x;
  int tx = tid & 15, ty = tid >> 4;
  __shared__ __align__(16) float As[16][68], Bs[16][68];
  float acc[4][4] = {};
  int arow = tid >> 2, akq = (tid & 3) * 4;
  int bkk = tid >> 4, bcol = (tid & 15) * 4;
  const float* Ap = A + (size_t)(m0 + arow)*ldA + akq;
  const float* Bp = Bm + (size_t)bkk*ldB + n0 + bcol;
  for (int k0 = 0; k0 < Kd; k0 += 16) {
    float4 a4 = *(const float4*)(Ap + k0);
    float4 b4 = *(const float4*)(Bp + (size_t)k0 * ldB);
    __syncthreads();
    As[akq+0][arow] = a4.x; As[akq+1][arow] = a4.y;
    As[akq+2][arow] = a4.z; As[akq+3][arow] = a4.w;
    *(float4*)&Bs[bkk][bcol] = b4;
    __syncthreads();
    #pragma unroll
    for (int kk = 0; kk < 16; kk++) {
      float av[4], bv[4];
      *(float4*)av = *(const float4*)&As[kk][ty*4];
      *(float4*)bv = *(const float4*)&Bs[kk][tx*4];
      #pragma unroll
      for (int i = 0; i < 4; i++)
        #pragma unroll
        for (int j = 0; j < 4; j++) acc[i][j] += av[i] * bv[j];
    }
  }
  #pragma unroll
  for (int i = 0; i < 4; i++) {
    int rr = m0 + ty*4 + i;
    float ov[4];
    #pragma unroll
    for (int j = 0; j < 4; j++) {
      float v = acc[i][j];
      if (MODE == 1) v = 2.f*v - ((rr == n0 + tx*4 + j) ? 1.f : 0.f);
      ov[j] = v;
    }
    *(float4*)&D[(size_t)rr*ldD + n0 + tx*4] = *(float4*)ov;
  }
}

// ---------------- column max over m (axis=1) ----------------
__global__ void k_colmax(const float* __restrict__ logit, float* __restrict__ cm) {
  int idx = blockIdx.x * 256 + threadIdx.x;          // B*N
  int b = idx >> 10, q = idx & 1023;
  const float* base = logit + (size_t)b*N_*N_ + q;
  float m = -3.4e38f;
  #pragma unroll 8
  for (int mm = 0; mm < N_; mm++) m = fmaxf(m, base[(size_t)mm * N_]);
  cm[idx] = m;
}

// ---------------- in-place row softmax of (logits - colmax) ----------------
__global__ __launch_bounds__(256) void k_softmax(float* __restrict__ S,
                                                 const float* __restrict__ cm) {
  int bm = blockIdx.x; int tid = threadIdx.x;
  int b = bm >> 10;
  float* row = S + (size_t)bm * N_;
  const float* cmb = cm + (size_t)b * N_;
  float v[4]; float mx = -3.4e38f;
  #pragma unroll
  for (int j = 0; j < 4; j++) { int q = tid + j*256; v[j] = row[q] - cmb[q]; mx = fmaxf(mx, v[j]); }
  #pragma unroll
  for (int off = 32; off; off >>= 1) mx = fmaxf(mx, __shfl_down(mx, off));
  __shared__ float sm[4], ss[4];
  if ((tid & 63) == 0) sm[tid >> 6] = mx;
  __syncthreads();
  mx = fmaxf(fmaxf(sm[0], sm[1]), fmaxf(sm[2], sm[3]));
  float e[4]; float s = 0.f;
  #pragma unroll
  for (int j = 0; j < 4; j++) { e[j] = expf(v[j] - mx); s += e[j]; }
  #pragma unroll
  for (int off = 32; off; off >>= 1) s += __shfl_down(s, off);
  if ((tid & 63) == 0) ss[tid >> 6] = s;
  __syncthreads();
  float inv = 1.f / (ss[0] + ss[1] + ss[2] + ss[3]);
  #pragma unroll
  for (int j = 0; j < 4; j++) row[tid + j*256] = e[j] * inv;
}

// ---------------- x_TAt (relayout to [b][n][c*L]) ----------------
__global__ __launch_bounds__(768) void k_xtat(const float* __restrict__ x,
    const float* __restrict__ Tout, float* __restrict__ xT2) {
  int bn = blockIdx.x; int b = bn >> 10, n = bn & 1023;
  __shared__ float xrow[768], Tl[576];
  int tid = threadIdx.x;
  int c = tid / 24, q = tid % 24;
  xrow[tid] = x[(((size_t)b*C_ + c)*N_ + n)*L_ + q];
  if (tid < 576) Tl[tid] = Tout[(size_t)b*576 + tid];
  __syncthreads();
  float acc = 0.f;
  #pragma unroll
  for (int ll = 0; ll < 24; ll++) acc += xrow[c*24 + ll] * Tl[ll*24 + q];
  xT2[(size_t)bn*768 + tid] = acc;
}

// ---------------- weight repack ----------------
__global__ void k_wrepack(const float* __restrict__ gcn_w, const float* __restrict__ conv1_w,
                          const float* __restrict__ time_w, float* __restrict__ wGT,
                          float* __restrict__ wCT, float* __restrict__ twT) {
  int idx = blockIdx.x * 256 + threadIdx.x;
  if (idx < 96*64)  { int f = idx >> 6, o = idx & 63; wGT[idx] = gcn_w[o*96 + f]; }
  if (idx < 32*64)  { int c = idx >> 6, o = idx & 63; wCT[idx] = conv1_w[o*32 + c]; }
  if (idx < 192*64) { int f = idx >> 6, o = idx & 63; twT[idx] = time_w[o*192 + f]; }
}

// ---------------- fused gcn + relu + time-conv + x_input + relu + LN-stats ----------------
constexpr int QB = 4;
constexpr int XTS = 776;
constexpr int GST = 64*26 + 8;
__global__ __launch_bounds__(384) void k_gcn_time(
    const float* __restrict__ xT2, const float* __restrict__ z1, const float* __restrict__ z2,
    const float* __restrict__ S, const float* __restrict__ x,
    const float* __restrict__ wGT, const float* __restrict__ wCT, const float* __restrict__ twT,
    const float* __restrict__ gcn_b, const float* __restrict__ time_b,
    const float* __restrict__ conv1_b, float* __restrict__ out, float* __restrict__ partials) {
  int blk = blockIdx.x;             // 4096 = B * 256
  int b = blk >> 8;
  int q0 = (blk & 255) * QB;
  int tid = threadIdx.x;
  __shared__ __align__(16) float xtS[QB*XTS], z1S[QB*XTS], z2S[QB*XTS];
  __shared__ __align__(16) float gS[QB*GST];
  __shared__ float sdS[QB];
  __shared__ float red[12];
  for (int t = tid; t < QB*768; t += 384) {
    int qi = t / 768, j = t % 768;
    size_t src = ((size_t)(b*N_ + q0 + qi))*768 + j;
    xtS[qi*XTS + j] = xT2[src];
    z1S[qi*XTS + j] = z1[src];
    z2S[qi*XTS + j] = z2[src];
  }
  if (tid < QB) { int q = q0 + tid; sdS[tid] = S[((size_t)b*N_ + q)*N_ + q]; }
  for (int t = tid; t < QB*64; t += 384) {
    int qi = t >> 6, i = t & 63;
    gS[qi*GST + i*26 + 0] = 0.f; gS[qi*GST + i*26 + 25] = 0.f;
  }
  __syncthreads();
  int og = tid / 24; int r = tid % 24; int qi = r / 6; int lg = r % 6;
  int o0 = og*4, l0 = lg*4;
  int q = q0 + qi;
  float acc[4][4] = {};
  float sd = sdS[qi];
  const float* xtp = &xtS[qi*XTS];
  const float* z1p = &z1S[qi*XTS];
  const float* z2p = &z2S[qi*XTS];
  for (int c = 0; c < C_; c++) {
    float b0[4], b1[4], b2[4], a0[4], a1[4], a2[4];
    *(float4*)b0 = *(const float4*)(xtp + c*24 + l0);
    *(float4*)b1 = *(const float4*)(z1p + c*24 + l0);
    *(float4*)b2 = *(const float4*)(z2p + c*24 + l0);
    *(float4*)a0 = *(const float4*)(wGT + (c*3+0)*64 + o0);
    *(float4*)a1 = *(const float4*)(wGT + (c*3+1)*64 + o0);
    *(float4*)a2 = *(const float4*)(wGT + (c*3+2)*64 + o0);
    float sb0[4] = {sd*b0[0], sd*b0[1], sd*b0[2], sd*b0[3]};
    #pragma unroll
    for (int i = 0; i < 4; i++)
      #pragma unroll
      for (int j = 0; j < 4; j++)
        acc[i][j] += a0[i]*sb0[j] + a1[i]*b1[j] + a2[i]*b2[j];
  }
  #pragma unroll
  for (int i = 0; i < 4; i++) {
    float gb = gcn_b[o0 + i];
    #pragma unroll
    for (int j = 0; j < 4; j++)
      gS[qi*GST + (o0+i)*26 + 1 + l0 + j] = fmaxf(acc[i][j] + gb, 0.f);
  }
  __syncthreads();
  float acc2[4][4] = {};
  const float* gp = &gS[qi*GST];
  for (int i2 = 0; i2 < CO_; i2++) {
    float gv[6];
    #pragma unroll
    for (int u = 0; u < 6; u++) gv[u] = gp[i2*26 + l0 + u];
    #pragma unroll
    for (int t = 0; t < 3; t++) {
      float a[4];
      *(float4*)a = *(const float4*)(twT + (i2*3+t)*64 + o0);
      #pragma unroll
      for (int i = 0; i < 4; i++)
        #pragma unroll
        for (int j = 0; j < 4; j++) acc2[i][j] += a[i] * gv[t + j];
    }
  }
  float accx[4][4] = {};
  const float* xb = x + ((size_t)b*C_*N_ + q)*L_ + l0;
  for (int c = 0; c < C_; c++) {
    float xv[4], a[4];
    *(float4*)xv = *(const float4*)(xb + (size_t)c*N_*L_);
    *(float4*)a  = *(const float4*)(wCT + c*64 + o0);
    #pragma unroll
    for (int i = 0; i < 4; i++)
      #pragma unroll
      for (int j = 0; j < 4; j++) accx[i][j] += a[i] * xv[j];
  }
  float s1 = 0.f, s2 = 0.f;
  #pragma unroll
  for (int i = 0; i < 4; i++) {
    float tb = time_b[o0 + i], cb = conv1_b[o0 + i];
    float ov[4];
    #pragma unroll
    for (int j = 0; j < 4; j++) {
      float pre = fmaxf(acc2[i][j] + tb + accx[i][j] + cb, 0.f);
      s1 += pre; s2 += pre * pre; ov[j] = pre;
    }
    *(float4*)&out[(((size_t)b*CO_ + o0 + i)*N_ + q)*L_ + l0] = *(float4*)ov;
  }
  #pragma unroll
  for (int off = 32; off; off >>= 1) { s1 += __shfl_down(s1, off); s2 += __shfl_down(s2, off); }
  if ((tid & 63) == 0) { red[(tid >> 6)*2] = s1; red[(tid >> 6)*2 + 1] = s2; }
  __syncthreads();
  if (tid == 0) {
    float t1 = 0.f, t2 = 0.f;
    for (int w = 0; w < 6; w++) { t1 += red[w*2]; t2 += red[w*2+1]; }
    partials[blk*2] = t1; partials[blk*2 + 1] = t2;
  }
}

__global__ __launch_bounds__(256) void k_bstats(const float* __restrict__ partials,
                                                float* __restrict__ bstats) {
  int b = blockIdx.x; int tid = threadIdx.x;
  __shared__ float r1[256], r2[256];
  r1[tid] = partials[(b*256 + tid)*2];
  r2[tid] = partials[(b*256 + tid)*2 + 1];
  __syncthreads();
  for (int off = 128; off; off >>= 1) {
    if (tid < off) { r1[tid] += r1[tid + off]; r2[tid] += r2[tid + off]; }
    __syncthreads();
  }
  if (tid == 0) { bstats[b*2] = r1[0]; bstats[b*2 + 1] = r2[0]; }
}

__global__ void k_ln(float* __restrict__ out, const float* __restrict__ bstats,
                     const float* __restrict__ lnw, const float* __restrict__ lnb) {
  size_t idx = (size_t)blockIdx.x * 256 + threadIdx.x;   // B*CO*N*L
  constexpr size_t PER = (size_t)CO_*N_*L_;
  int b = (int)(idx / PER); size_t r = idx % PER;
  float cnt = (float)PER;
  float mu = bstats[b*2] / cnt;
  float var = bstats[b*2 + 1] / cnt - mu*mu;
  float inv = rsqrtf(var + 1e-5f);
  out[idx] = (out[idx] - mu) * inv * lnw[r] + lnb[r];
}
} // namespace

extern "C" void kernel_launch(void* const* d_in, const int* in_sizes, int n_in,
                              void* d_out, int out_size, void* d_ws, size_t ws_size,
                              hipStream_t stream) {
  const float* x        = (const float*)d_in[0];
  const float* supports = (const float*)d_in[1];
  const float* conv1_w  = (const float*)d_in[2];
  const float* conv1_b  = (const float*)d_in[3];
  const float* t1w      = (const float*)d_in[4];
  const float* t2w      = (const float*)d_in[5];
  const float* t_w      = (const float*)d_in[6];
  const float* t_b      = (const float*)d_in[7];
  const float* t_v      = (const float*)d_in[8];
  const float* s1w      = (const float*)d_in[9];
  const float* s2w      = (const float*)d_in[10];
  const float* s_w      = (const float*)d_in[11];
  const float* s_b      = (const float*)d_in[12];
  const float* s_v      = (const float*)d_in[13];
  const float* gcn_w    = (const float*)d_in[14];
  const float* gcn_b    = (const float*)d_in[15];
  const float* time_w   = (const float*)d_in[16];
  const float* time_b   = (const float*)d_in[17];
  const float* ln_w     = (const float*)d_in[18];
  const float* ln_b     = (const float*)d_in[19];

  float* out  = (float*)d_out;
  float* Sout = out + S_OFF;      // [B][N][N]: logits -> S_coef in place
  float* Tout = out + T_OFF;      // [B][L][L]
  u16*   outU = (u16*)d_out;      // scratch region (rewritten by k_gcn_time/k_ln)
  float* ws   = (float*)d_ws;

  u16*   rawp = (u16*)(ws + O_RAW);
  float* zz1  = ws + O_RAW;       // alias: rawp dead before zz1 written
  float* zz2  = ws + O_Z2;
  float* xT2  = ws + O_XT2;
  float* sup2 = ws + O_SUP2;
  float* f1t  = ws + O_F1T;
  float* f1s  = ws + O_F1S;
  float* f2t  = ws + O_F2T;
  float* f2s  = ws + O_F2S;
  float* g_t  = ws + O_GT;
  float* g_s  = ws + O_GS;
  float* cm   = ws + O_CM;
  float* twT  = ws + O_TWT;
  float* wGT  = ws + O_WGT;
  float* wCT  = ws + O_WCT;
  float* part = ws + O_PART;
  float* bst  = ws + O_BST;

  u16* A1p = outU + OS_A1;
  u16* A2p = outU + OS_A2;
  u16* Xp  = outU + OS_XP;
  u16* svp = outU + OS_SV;

  constexpr long NN = (long)N_*N_;

  k_f1<<<1536, 256, 0, stream>>>(x, t1w, s1w, f1t, f1s);
  k_f2t<<<B_*C_, 768, 0, stream>>>(x, t2w, f2t);
  k_f2s<<<2048, 256, 0, stream>>>(x, s2w, f2s);
  k_gt<<<B_*L_, 1024, 0, stream>>>(f1t, t_w, g_t);
  k_gs<<<2048, 256, 0, stream>>>(f1s, s_w, g_s);
  k_tatt<<<B_, 576, 0, stream>>>(g_t, f2t, t_b, t_v, Tout);
  k_raws_pack<<<8192, 256, 0, stream>>>(g_s, f2s, s_b, rawp);
  k_pack_sv<<<512, 256, 0, stream>>>(s_v, svp);
  // supports @ supports -> T2 basis (f32, small)
  k_mm<1><<<dim3(16, 16, 1), 256, 0, stream>>>(supports, supports, sup2,
                                               N_, N_, N_, N_, 0, 0, 0);
  // logits = s_v @ raw_s  (bf16 MFMA, into d_out S region)
  k_mfma<0><<<dim3(8, 8, B_), 256, 0, stream>>>(svp, svp, rawp, Sout, Sout,
                                                N_, N_, 0, NN, NN);
  k_colmax<<<64, 256, 0, stream>>>(Sout, cm);
  k_softmax<<<B_*N_, 256, 0, stream>>>(Sout, cm);
  k_xtat<<<B_*N_, 768, 0, stream>>>(x, Tout, xT2);
  k_pack_cheb<<<8192, 256, 0, stream>>>(Sout, supports, sup2, A1p, A2p);
  k_pack_x<<<6144, 256, 0, stream>>>(xT2, Xp);
  // z1 = (S.*sup) @ X ; z2 = (S.*sup2) @ X  (dual bf16 MFMA)
  k_mfma<1><<<dim3(6, 8, B_), 256, 0, stream>>>(A1p, A2p, Xp, zz1, zz2,
                                                N_, 768, NN, (long)N_*768, (long)N_*768);
  k_wrepack<<<48, 256, 0, stream>>>(gcn_w, conv1_w, time_w, wGT, wCT, twT);
  k_gcn_time<<<4096, 384, 0, stream>>>(xT2, zz1, zz2, Sout, x, wGT, wCT, twT,
                                       gcn_b, time_b, conv1_b, out, part);
  k_bstats<<<B_, 256, 0, stream>>>(part, bst);
  k_ln<<<98304, 256, 0, stream>>>(out, bst, ln_w, ln_b);
}

// Round 3
// 760.337 us; speedup vs baseline: 2.7100x; 1.4527x over previous
//
#include <hip/hip_runtime.h>
#include <cstddef>

namespace {
constexpr int B_ = 16, C_ = 32, N_ = 1024, L_ = 24, CO_ = 64;

constexpr size_t S_OFF = (size_t)B_*CO_*N_*L_;            // 25165824 floats
constexpr size_t T_OFF = S_OFF + (size_t)B_*N_*N_;        // 41943040

// ---- workspace layout (f32 units) ----
constexpr size_t O_GCN  = 0;                              // gcn bf16 [B][N][26][64] = 27.26M u16 (rawp aliases first 16M u16)
constexpr size_t O_XTLC = 13631488;                       // xT bf16 [B][N][768] (l*32+c)
constexpr size_t O_XR   = 19922944;                       // x  bf16 [B][N][768] (l*32+c)
constexpr size_t O_Z1   = 26214400;                       // z1 bf16 [B][N][768]
constexpr size_t O_Z2   = 32505856;                       // z2 bf16
constexpr size_t O_F1T  = 38797312;
constexpr size_t O_F1S  = 39190528;
constexpr size_t O_F2T  = 39583744;
constexpr size_t O_F2S  = 39596032;
constexpr size_t O_GT   = 40120320;
constexpr size_t O_GS   = 40132608;
constexpr size_t O_CM   = 40656896;
constexpr size_t O_WAP  = 40673280;                       // GA weights packed (6144 u16)
constexpr size_t O_W2P  = 40676352;                       // GB weights packed (14336 u16)
constexpr size_t O_PART = 40683520;                       // [3072][2]
constexpr size_t O_BST  = 40689664;                       // [B][2]

// ---- d_out scratch (u16 units), region [0, S_OFF floats) dead until k_gb ----
constexpr size_t OS_A1  = 0;                              // A1 packed bf16 [B][N*N]
constexpr size_t OS_A2  = OS_A1 + (size_t)B_*N_*N_;
constexpr size_t OS_XP  = OS_A2 + (size_t)B_*N_*N_;       // cheb B packed [B][N*768]
constexpr size_t OS_SV  = OS_XP + (size_t)B_*N_*768;      // s_v packed [N*N]
constexpr size_t OS_SUP2= OS_SV + (size_t)N_*N_;          // sup2 f32 [N][N] (2M u16)

typedef unsigned short u16;
typedef __attribute__((ext_vector_type(8))) short short8v;
typedef __attribute__((ext_vector_type(4))) float f32x4;

__device__ __forceinline__ u16 f2bf(float x) {
  unsigned u = __builtin_bit_cast(unsigned, x);
  return (u16)((u + 0x7fffu + ((u >> 16) & 1u)) >> 16);
}
__device__ __forceinline__ float bf2f(u16 v) {
  return __builtin_bit_cast(float, ((unsigned)v) << 16);
}
__device__ __forceinline__ void gl_lds16(const void* g, void* l) {
  __builtin_amdgcn_global_load_lds(
      (const __attribute__((address_space(1))) unsigned int*)g,
      (__attribute__((address_space(3))) unsigned int*)l, 16, 0, 0);
}

// ---------------- stage 1: fused channel reductions over x ----------------
__global__ void k_f1(const float* __restrict__ x, const float* __restrict__ t1w,
                     const float* __restrict__ s1w, float* __restrict__ f1t,
                     float* __restrict__ f1s) {
  int idx = blockIdx.x * 256 + threadIdx.x;          // B*N*L
  int b = idx / (N_*L_); int r = idx % (N_*L_); int n = r / L_; int l = r % L_;
  const float* xp = x + ((size_t)b*C_*N_ + n)*L_ + l;
  float a1 = 0.f, a2 = 0.f;
  #pragma unroll
  for (int c = 0; c < C_; c++) {
    float v = xp[(size_t)c*N_*L_];
    a1 += v * t1w[c]; a2 += v * s1w[c];
  }
  f1t[((size_t)b*L_ + l)*N_ + n] = a1;
  f1s[idx] = a2;
}

__global__ __launch_bounds__(768) void k_f2t(const float* __restrict__ x,
    const float* __restrict__ w, float* __restrict__ f2t) {
  int bc = blockIdx.x; int tid = threadIdx.x;
  int nsub = tid / 24, l = tid % 24;
  const float* xp = x + (size_t)bc*N_*L_;
  float a = 0.f;
  for (int i = 0; i < 32; i++) {
    int n = nsub + i*32;
    a += xp[(size_t)n*24 + l] * w[n];
  }
  __shared__ float s[768];
  s[tid] = a; __syncthreads();
  for (int off = 16; off >= 1; off >>= 1) {
    if (nsub < off) s[tid] += s[tid + off*24];
    __syncthreads();
  }
  if (tid < 24) f2t[(size_t)bc*24 + tid] = s[tid];
}

__global__ void k_f2s(const float* __restrict__ x, const float* __restrict__ w,
                      float* __restrict__ f2s) {
  int idx = blockIdx.x * 256 + threadIdx.x;          // B*C*N
  const float* xp = x + (size_t)idx * L_;
  float a = 0.f;
  #pragma unroll
  for (int l = 0; l < L_; l++) a += xp[l] * w[l];
  f2s[idx] = a;
}

__global__ __launch_bounds__(1024) void k_gt(const float* __restrict__ f1t,
    const float* __restrict__ tw, float* __restrict__ g_t) {
  int bl = blockIdx.x; int tid = threadIdx.x;
  int nsub = tid >> 5, c = tid & 31;
  const float* f = f1t + (size_t)bl * N_;
  float a = 0.f;
  for (int i = 0; i < 32; i++) {
    int n = nsub + (i << 5);
    a += f[n] * tw[n*32 + c];
  }
  __shared__ float s[1024];
  s[tid] = a; __syncthreads();
  for (int off = 512; off >= 32; off >>= 1) {
    if (tid < off) s[tid] += s[tid + off];
    __syncthreads();
  }
  if (tid < 32) g_t[(size_t)bl*32 + tid] = s[tid];
}

__global__ void k_gs(const float* __restrict__ f1s, const float* __restrict__ sw,
                     float* __restrict__ g_s) {
  int idx = blockIdx.x * 256 + threadIdx.x;          // B*N*C
  int bn = idx >> 5, c = idx & 31;
  const float* f = f1s + (size_t)bn * L_;
  float a = 0.f;
  #pragma unroll
  for (int l = 0; l < L_; l++) a += f[l] * sw[l*32 + c];
  g_s[idx] = a;
}

// ---------------- temporal attention ----------------
__global__ __launch_bounds__(576) void k_tatt(const float* __restrict__ g_t,
    const float* __restrict__ f2t, const float* __restrict__ tb,
    const float* __restrict__ tv, float* __restrict__ Tout) {
  int b = blockIdx.x; int tid = threadIdx.x;
  int l = tid / 24, q = tid % 24;
  __shared__ float rawS[576], logS[576], cmS[24], rmS[24], rsS[24];
  float acc = tb[tid];
  const float* g = g_t + ((size_t)b*L_ + l)*C_;
  const float* f = f2t + (size_t)b*C_*L_ + q;
  #pragma unroll
  for (int c = 0; c < C_; c++) acc += g[c] * f[(size_t)c*L_];
  rawS[tid] = 1.f / (1.f + expf(-acc));
  __syncthreads();
  float lg = 0.f;
  #pragma unroll
  for (int k = 0; k < L_; k++) lg += tv[l*L_ + k] * rawS[k*L_ + q];
  logS[tid] = lg;
  __syncthreads();
  if (l == 0) { float m = -3.4e38f; for (int mm = 0; mm < L_; mm++) m = fmaxf(m, logS[mm*L_ + q]); cmS[q] = m; }
  __syncthreads();
  float lc = lg - cmS[q];
  logS[tid] = lc;
  __syncthreads();
  if (q == 0) { float m = -3.4e38f; for (int qq = 0; qq < L_; qq++) m = fmaxf(m, logS[l*L_ + qq]); rmS[l] = m; }
  __syncthreads();
  float e = expf(lc - rmS[l]);
  logS[tid] = e;
  __syncthreads();
  if (q == 0) { float s = 0.f; for (int qq = 0; qq < L_; qq++) s += logS[l*L_ + qq]; rsS[l] = s; }
  __syncthreads();
  Tout[(size_t)b*576 + q*24 + l] = e / rsS[l];
}

// ---------------- raw_s sigmoid -> packed-B bf16 directly ----------------
__global__ void k_raws_pack(const float* __restrict__ g_s, const float* __restrict__ f2s,
                            const float* __restrict__ sb, u16* __restrict__ rawp) {
  int t = blockIdx.x * 256 + threadIdx.x;
  int b = t >> 17, tt = t & 131071;
  int fi = tt >> 6, l = tt & 63;
  int kb = fi >> 6, nb = fi & 63;
  int m  = (nb << 4) + (l & 15);
  int n0 = (kb << 5) + ((l >> 4) << 3);
  const float* f = f2s + ((size_t)b*C_*N_) + m;
  float fv[C_];
  #pragma unroll
  for (int c = 0; c < C_; c++) fv[c] = f[(size_t)c << 10];
  const float* g = g_s + (((size_t)b << 10) + n0) * C_;
  u16* d = rawp + ((size_t)b << 20) + ((size_t)fi << 9) + (l << 3);
  #pragma unroll
  for (int j = 0; j < 8; j++) {
    float a = sb[(size_t)(n0 + j)*N_ + m];
    const float* gr = g + j*C_;
    #pragma unroll
    for (int c = 0; c < C_; c++) a += gr[c] * fv[c];
    d[j] = f2bf(1.f / (1.f + expf(-a)));
  }
}

// ---------------- pack s_v into A-operand bf16 layout ----------------
__global__ void k_pack_sv(const float* __restrict__ sv, u16* __restrict__ svp) {
  int t = blockIdx.x * 256 + threadIdx.x;
  int fi = t >> 6, l = t & 63;
  int mg = fi >> 5, kg = fi & 31;
  int row = (mg << 4) + (l & 15);
  int k   = (kg << 5) + ((l >> 4) << 3);
  const float* s = sv + (size_t)row*N_ + k;
  u16* d = svp + ((size_t)fi << 9) + (l << 3);
  #pragma unroll
  for (int j = 0; j < 8; j++) d[j] = f2bf(s[j]);
}

// ---------------- pack A1=S.*sup, A2=S.*sup2 ----------------
__global__ void k_pack_cheb(const float* __restrict__ S, const float* __restrict__ sup,
                            const float* __restrict__ sup2, u16* __restrict__ A1p,
                            u16* __restrict__ A2p) {
  int t = blockIdx.x * 256 + threadIdx.x;
  int b = t >> 17, tt = t & 131071;
  int fi = tt >> 6, l = tt & 63;
  int mg = fi >> 5, kg = fi & 31;
  int row = (mg << 4) + (l & 15);
  int k   = (kg << 5) + ((l >> 4) << 3);
  const float* sp = S + ((size_t)b << 20) + (size_t)row*N_ + k;
  const float* p1 = sup  + (size_t)row*N_ + k;
  const float* p2 = sup2 + (size_t)row*N_ + k;
  size_t off = ((size_t)b << 20) + ((size_t)fi << 9) + (l << 3);
  #pragma unroll
  for (int j = 0; j < 8; j++) {
    float s = sp[j];
    A1p[off + j] = f2bf(s * p1[j]);
    A2p[off + j] = f2bf(s * p2[j]);
  }
}

// ---------------- pack xT (bf16, l*32+c order) into cheb B-operand ----------------
__global__ void k_pack_x(const u16* __restrict__ xTlc, u16* __restrict__ Xp) {
  int t = blockIdx.x * 256 + threadIdx.x;            // B * 98304
  int b = t / 98304, tt = t % 98304;
  int fi = tt >> 6, l = tt & 63;
  int kb = fi / 48, nb = fi % 48;
  int col = (nb << 4) + (l & 15);
  int kr  = (kb << 5) + ((l >> 4) << 3);
  const u16* xs = xTlc + ((size_t)b*N_ + kr)*768 + col;
  u16* d = Xp + (size_t)b*786432 + ((size_t)fi << 9) + (l << 3);
  #pragma unroll
  for (int j = 0; j < 8; j++) d[j] = xs[(size_t)j*768];
}

// ---------------- bf16 MFMA GEMM, 128x128 tile. OUTBF: bf16 outputs ----------------
template <int DUAL, int OUTBF>
__global__ __launch_bounds__(256) void k_mfma(
    const u16* __restrict__ Ap, const u16* __restrict__ A2p,
    const u16* __restrict__ Bp, void* __restrict__ D1, void* __restrict__ D2,
    int Kd, int Ncols, long sA, long sB, long sD) {
  int b = blockIdx.z;
  const u16* A1 = Ap + (size_t)b * sA;
  const u16* A2 = DUAL ? (A2p + (size_t)b * sA) : nullptr;
  const u16* Bm = Bp + (size_t)b * sB;
  int mg0 = blockIdx.y * 8;
  int ng0 = blockIdx.x * 8;
  int Kg = Kd >> 5;
  int Ng = Ncols >> 4;
  int tid = threadIdx.x;
  int w = tid >> 6, lane = tid & 63;
  int wr = w >> 1, wc = w & 1;
  __shared__ __align__(16) u16 smem[(DUAL ? 3 : 2) * 8192];
  u16* As  = smem;
  u16* A2s = smem + 8192;
  u16* Bs  = smem + (DUAL ? 16384 : 8192);
  f32x4 acc1[4][4] = {};
  f32x4 acc2[4][4] = {};

  for (int k0 = 0; k0 < Kg; k0 += 2) {
    __syncthreads();
    #pragma unroll
    for (int i = 0; i < 4; i++) {
      int f = w + 4*i;
      int r = f >> 1, c = f & 1;
      size_t goff = (((size_t)(mg0 + r)) * Kg + (k0 + c)) * 512 + (lane << 3);
      gl_lds16(A1 + goff, &As[f * 512]);
      if (DUAL) gl_lds16(A2 + goff, &A2s[f * 512]);
      int cb = f >> 3, tn = f & 7;
      size_t boff = (((size_t)(k0 + cb)) * Ng + (ng0 + tn)) * 512 + (lane << 3);
      gl_lds16(Bm + boff, &Bs[f * 512]);
    }
    __syncthreads();
    #pragma unroll
    for (int kk = 0; kk < 2; kk++) {
      short8v bq[4], av[4], av2[4];
      #pragma unroll
      for (int j = 0; j < 4; j++)
        bq[j] = *(const short8v*)&Bs[(kk*8 + wc*4 + j)*512 + (lane << 3)];
      #pragma unroll
      for (int i = 0; i < 4; i++) {
        av[i] = *(const short8v*)&As[((wr*4 + i)*2 + kk)*512 + (lane << 3)];
        if (DUAL)
          av2[i] = *(const short8v*)&A2s[((wr*4 + i)*2 + kk)*512 + (lane << 3)];
      }
      #pragma unroll
      for (int i = 0; i < 4; i++)
        #pragma unroll
        for (int j = 0; j < 4; j++) {
          acc1[i][j] = __builtin_amdgcn_mfma_f32_16x16x32_bf16(av[i], bq[j], acc1[i][j], 0, 0, 0);
          if (DUAL)
            acc2[i][j] = __builtin_amdgcn_mfma_f32_16x16x32_bf16(av2[i], bq[j], acc2[i][j], 0, 0, 0);
        }
    }
  }
  #pragma unroll
  for (int i = 0; i < 4; i++) {
    int row = (mg0 + wr*4 + i)*16 + ((lane >> 4) << 2);
    #pragma unroll
    for (int j = 0; j < 4; j++) {
      int col = (ng0 + wc*4 + j)*16 + (lane & 15);
      #pragma unroll
      for (int r = 0; r < 4; r++) {
        size_t o = (size_t)(row + r)*Ncols + col;
        if (OUTBF) {
          ((u16*)D1)[(size_t)b*sD + o] = f2bf(acc1[i][j][r]);
          if (DUAL) ((u16*)D2)[(size_t)b*sD + o] = f2bf(acc2[i][j][r]);
        } else {
          ((float*)D1)[(size_t)b*sD + o] = acc1[i][j][r];
          if (DUAL) ((float*)D2)[(size_t)b*sD + o] = acc2[i][j][r];
        }
      }
    }
  }
}

// ---------------- f32 tiled GEMM (supports@supports only) ----------------
template <int MODE>
__global__ __launch_bounds__(256) void k_mm(const float* __restrict__ A,
    const float* __restrict__ Bm, float* __restrict__ D, int Kd,
    int ldA, int ldB, int ldD) {
  int n0 = blockIdx.x * 64, m0 = blockIdx.y * 64;
  int tid = threadIdx.x;
  int tx = tid & 15, ty = tid >> 4;
  __shared__ __align__(16) float As[16][68], Bs[16][68];
  float acc[4][4] = {};
  int arow = tid >> 2, akq = (tid & 3) * 4;
  int bkk = tid >> 4, bcol = (tid & 15) * 4;
  const float* Ap = A + (size_t)(m0 + arow)*ldA + akq;
  const float* Bp = Bm + (size_t)bkk*ldB + n0 + bcol;
  for (int k0 = 0; k0 < Kd; k0 += 16) {
    float4 a4 = *(const float4*)(Ap + k0);
    float4 b4 = *(const float4*)(Bp + (size_t)k0 * ldB);
    __syncthreads();
    As[akq+0][arow] = a4.x; As[akq+1][arow] = a4.y;
    As[akq+2][arow] = a4.z; As[akq+3][arow] = a4.w;
    *(float4*)&Bs[bkk][bcol] = b4;
    __syncthreads();
    #pragma unroll
    for (int kk = 0; kk < 16; kk++) {
      float av[4], bv[4];
      *(float4*)av = *(const float4*)&As[kk][ty*4];
      *(float4*)bv = *(const float4*)&Bs[kk][tx*4];
      #pragma unroll
      for (int i = 0; i < 4; i++)
        #pragma unroll
        for (int j = 0; j < 4; j++) acc[i][j] += av[i] * bv[j];
    }
  }
  #pragma unroll
  for (int i = 0; i < 4; i++) {
    int rr = m0 + ty*4 + i;
    float ov[4];
    #pragma unroll
    for (int j = 0; j < 4; j++) {
      float v = acc[i][j];
      if (MODE == 1) v = 2.f*v - ((rr == n0 + tx*4 + j) ? 1.f : 0.f);
      ov[j] = v;
    }
    *(float4*)&D[(size_t)rr*ldD + n0 + tx*4] = *(float4*)ov;
  }
}

// ---------------- column max / row softmax ----------------
__global__ void k_colmax(const float* __restrict__ logit, float* __restrict__ cm) {
  int idx = blockIdx.x * 256 + threadIdx.x;
  int b = idx >> 10, q = idx & 1023;
  const float* base = logit + (size_t)b*N_*N_ + q;
  float m = -3.4e38f;
  #pragma unroll 8
  for (int mm = 0; mm < N_; mm++) m = fmaxf(m, base[(size_t)mm * N_]);
  cm[idx] = m;
}

__global__ __launch_bounds__(256) void k_softmax(float* __restrict__ S,
                                                 const float* __restrict__ cm) {
  int bm = blockIdx.x; int tid = threadIdx.x;
  int b = bm >> 10;
  float* row = S + (size_t)bm * N_;
  const float* cmb = cm + (size_t)b * N_;
  float v[4]; float mx = -3.4e38f;
  #pragma unroll
  for (int j = 0; j < 4; j++) { int q = tid + j*256; v[j] = row[q] - cmb[q]; mx = fmaxf(mx, v[j]); }
  #pragma unroll
  for (int off = 32; off; off >>= 1) mx = fmaxf(mx, __shfl_down(mx, off));
  __shared__ float sm[4], ss[4];
  if ((tid & 63) == 0) sm[tid >> 6] = mx;
  __syncthreads();
  mx = fmaxf(fmaxf(sm[0], sm[1]), fmaxf(sm[2], sm[3]));
  float e[4]; float s = 0.f;
  #pragma unroll
  for (int j = 0; j < 4; j++) { e[j] = expf(v[j] - mx); s += e[j]; }
  #pragma unroll
  for (int off = 32; off; off >>= 1) s += __shfl_down(s, off);
  if ((tid & 63) == 0) ss[tid >> 6] = s;
  __syncthreads();
  float inv = 1.f / (ss[0] + ss[1] + ss[2] + ss[3]);
  #pragma unroll
  for (int j = 0; j < 4; j++) row[tid + j*256] = e[j] * inv;
}

// ---------------- x_TAt: bf16 (l*32+c) order, + x relayout ----------------
__global__ __launch_bounds__(768) void k_xtat(const float* __restrict__ x,
    const float* __restrict__ Tout, u16* __restrict__ xTlc, u16* __restrict__ xr) {
  int bn = blockIdx.x; int b = bn >> 10, n = bn & 1023;
  __shared__ float xrow[768], Tl[576];
  int tid = threadIdx.x;
  int c = tid / 24, q = tid % 24;
  float xv = x[(((size_t)b*C_ + c)*N_ + n)*L_ + q];
  xrow[tid] = xv;
  if (tid < 576) Tl[tid] = Tout[(size_t)b*576 + tid];
  xr[(size_t)bn*768 + q*32 + c] = f2bf(xv);
  __syncthreads();
  float acc = 0.f;
  #pragma unroll
  for (int ll = 0; ll < 24; ll++) acc += xrow[c*24 + ll] * Tl[ll*24 + q];
  xTlc[(size_t)bn*768 + q*32 + c] = f2bf(acc);
}

// ---------------- weight packing for GA/GB ----------------
__global__ void k_wpack(const float* __restrict__ gcn_w, const float* __restrict__ time_w,
                        const float* __restrict__ conv1_w, u16* __restrict__ WAp,
                        u16* __restrict__ W2p) {
  int t = blockIdx.x * 256 + threadIdx.x;
  if (t < 6144) {
    int fi = t >> 9, l = (t >> 3) & 63, j = t & 7;
    int kg = fi >> 2, cf = fi & 3;
    int o = cf*16 + (l & 15), c = ((l >> 4) << 3) + j;
    WAp[t] = f2bf(gcn_w[o*96 + c*3 + kg]);
  }
  if (t < 14336) {
    int fi = t >> 9, l = (t >> 3) & 63, j = t & 7;
    int kg = fi >> 2, cf = fi & 3;
    int o2 = cf*16 + (l & 15), kk = ((l >> 4) << 3) + j;
    float v;
    if (kg < 6) { int tt = kg >> 1, i = (kg & 1)*32 + kk; v = time_w[o2*192 + i*3 + tt]; }
    else v = conv1_w[o2*32 + kk];
    W2p[t] = f2bf(v);
  }
}

// ---------------- zero gcn l-pads ----------------
__global__ void k_zpad(u16* __restrict__ gcn) {
  int t = blockIdx.x * 256 + threadIdx.x;            // 524288
  int o4 = t & 15, rest = t >> 4;
  int half = rest & 1, bn = rest >> 1;               // bn < 16384
  size_t off = ((size_t)bn*26 + half*25)*64 + o4*4;
  *(unsigned long long*)&gcn[off] = 0ull;
}

// ---------------- GA: gcn = relu(W[64x96] @ F) , reg-only MFMA ----------------
__global__ __launch_bounds__(256) void k_ga(const u16* __restrict__ xTlc,
    const u16* __restrict__ z1, const u16* __restrict__ z2,
    const float* __restrict__ S, const u16* __restrict__ WAp,
    const float* __restrict__ gcn_b, u16* __restrict__ gcn) {
  int blk = blockIdx.x;                              // 3072 = B*192
  int b = blk / 192, mt = blk % 192;
  int tid = threadIdx.x, w = tid >> 6, lane = tid & 63;
  int lm = lane & 15, hi = lane >> 4;
  short8v Bf[3][4];
  #pragma unroll
  for (int kg = 0; kg < 3; kg++)
    #pragma unroll
    for (int cf = 0; cf < 4; cf++)
      Bf[kg][cf] = *(const short8v*)&WAp[(kg*4 + cf)*512 + lane*8];
  f32x4 acc[2][4] = {};
  #pragma unroll
  for (int rf = 0; rf < 2; rf++) {
    int row = mt*128 + (w*2 + rf)*16 + lm;
    size_t ba = (size_t)b*786432 + (size_t)row*32 + hi*8;
    short8v a0 = *(const short8v*)&xTlc[ba];
    short8v a1 = *(const short8v*)&z1[ba];
    short8v a2 = *(const short8v*)&z2[ba];
    int n = row / 24;
    float sd = S[((size_t)b << 20) + (size_t)n*1025];
    #pragma unroll
    for (int j = 0; j < 8; j++)
      a0[j] = (short)f2bf(bf2f((u16)a0[j]) * sd);
    #pragma unroll
    for (int cf = 0; cf < 4; cf++) {
      acc[rf][cf] = __builtin_amdgcn_mfma_f32_16x16x32_bf16(a0, Bf[0][cf], acc[rf][cf], 0, 0, 0);
      acc[rf][cf] = __builtin_amdgcn_mfma_f32_16x16x32_bf16(a1, Bf[1][cf], acc[rf][cf], 0, 0, 0);
      acc[rf][cf] = __builtin_amdgcn_mfma_f32_16x16x32_bf16(a2, Bf[2][cf], acc[rf][cf], 0, 0, 0);
    }
  }
  #pragma unroll
  for (int rf = 0; rf < 2; rf++) {
    int rbase = mt*128 + (w*2 + rf)*16 + hi*4;
    #pragma unroll
    for (int cf = 0; cf < 4; cf++) {
      int o = cf*16 + lm;
      float gb = gcn_b[o];
      #pragma unroll
      for (int r = 0; r < 4; r++) {
        int row = rbase + r;
        int n = row / 24, l = row - 24*n;
        gcn[(((size_t)b*1024 + n)*26 + l + 1)*64 + o] = f2bf(fmaxf(acc[rf][cf][r] + gb, 0.f));
      }
    }
  }
}

// ---------------- GB: pre = relu(timeW@G_im2col + conv1W@x + biases), + LN partials ----------------
__global__ __launch_bounds__(256) void k_gb(const u16* __restrict__ gcn,
    const u16* __restrict__ xr, const u16* __restrict__ W2p,
    const float* __restrict__ time_b, const float* __restrict__ conv1_b,
    float* __restrict__ out, float* __restrict__ partials) {
  int blk = blockIdx.x;                              // 3072
  int b = blk / 192, mt = blk % 192;
  int tid = threadIdx.x, w = tid >> 6, lane = tid & 63;
  int lm = lane & 15, hi = lane >> 4;
  f32x4 acc[2][4] = {};
  #pragma unroll
  for (int g = 0; g < 7; g++) {
    short8v Bf[4];
    #pragma unroll
    for (int cf = 0; cf < 4; cf++)
      Bf[cf] = *(const short8v*)&W2p[(g*4 + cf)*512 + lane*8];
    #pragma unroll
    for (int rf = 0; rf < 2; rf++) {
      int row = mt*128 + (w*2 + rf)*16 + lm;
      short8v a;
      if (g < 6) {
        int n = row / 24, l = row - 24*n;
        int ts = g >> 1, o0 = (g & 1)*32;
        a = *(const short8v*)&gcn[(((size_t)b*1024 + n)*26 + l + ts)*64 + o0 + hi*8];
      } else {
        a = *(const short8v*)&xr[(size_t)b*786432 + (size_t)row*32 + hi*8];
      }
      #pragma unroll
      for (int cf = 0; cf < 4; cf++)
        acc[rf][cf] = __builtin_amdgcn_mfma_f32_16x16x32_bf16(a, Bf[cf], acc[rf][cf], 0, 0, 0);
    }
  }
  float s1 = 0.f, s2 = 0.f;
  #pragma unroll
  for (int rf = 0; rf < 2; rf++) {
    int rbase = mt*128 + (w*2 + rf)*16 + hi*4;
    int n = rbase / 24, l0 = rbase - 24*n;
    #pragma unroll
    for (int cf = 0; cf < 4; cf++) {
      int o2 = cf*16 + lm;
      float bias = time_b[o2] + conv1_b[o2];
      float ov[4];
      #pragma unroll
      for (int r = 0; r < 4; r++) {
        float pre = fmaxf(acc[rf][cf][r] + bias, 0.f);
        s1 += pre; s2 += pre*pre; ov[r] = pre;
      }
      *(float4*)&out[(((size_t)b*64 + o2)*1024 + n)*24 + l0] = *(float4*)ov;
    }
  }
  #pragma unroll
  for (int off = 32; off; off >>= 1) { s1 += __shfl_down(s1, off); s2 += __shfl_down(s2, off); }
  __shared__ float red[8];
  if (lane == 0) { red[w*2] = s1; red[w*2 + 1] = s2; }
  __syncthreads();
  if (tid == 0) {
    float t1 = 0.f, t2 = 0.f;
    for (int ww = 0; ww < 4; ww++) { t1 += red[ww*2]; t2 += red[ww*2 + 1]; }
    partials[blk*2] = t1; partials[blk*2 + 1] = t2;
  }
}

__global__ __launch_bounds__(256) void k_bstats(const float* __restrict__ partials,
                                                float* __restrict__ bstats) {
  int b = blockIdx.x; int tid = threadIdx.x;
  __shared__ float r1[256], r2[256];
  r1[tid] = (tid < 192) ? partials[(b*192 + tid)*2] : 0.f;
  r2[tid] = (tid < 192) ? partials[(b*192 + tid)*2 + 1] : 0.f;
  __syncthreads();
  for (int off = 128; off; off >>= 1) {
    if (tid < off) { r1[tid] += r1[tid + off]; r2[tid] += r2[tid + off]; }
    __syncthreads();
  }
  if (tid == 0) { bstats[b*2] = r1[0]; bstats[b*2 + 1] = r2[0]; }
}

__global__ void k_ln(float* __restrict__ out, const float* __restrict__ bstats,
                     const float* __restrict__ lnw, const float* __restrict__ lnb) {
  size_t idx = (size_t)blockIdx.x * 256 + threadIdx.x;
  constexpr size_t PER = (size_t)CO_*N_*L_;
  int b = (int)(idx / PER); size_t r = idx % PER;
  float cnt = (float)PER;
  float mu = bstats[b*2] / cnt;
  float var = bstats[b*2 + 1] / cnt - mu*mu;
  float inv = rsqrtf(var + 1e-5f);
  out[idx] = (out[idx] - mu) * inv * lnw[r] + lnb[r];
}
} // namespace

extern "C" void kernel_launch(void* const* d_in, const int* in_sizes, int n_in,
                              void* d_out, int out_size, void* d_ws, size_t ws_size,
                              hipStream_t stream) {
  const float* x        = (const float*)d_in[0];
  const float* supports = (const float*)d_in[1];
  const float* conv1_w  = (const float*)d_in[2];
  const float* conv1_b  = (const float*)d_in[3];
  const float* t1w      = (const float*)d_in[4];
  const float* t2w      = (const float*)d_in[5];
  const float* t_w      = (const float*)d_in[6];
  const float* t_b      = (const float*)d_in[7];
  const float* t_v      = (const float*)d_in[8];
  const float* s1w      = (const float*)d_in[9];
  const float* s2w      = (const float*)d_in[10];
  const float* s_w      = (const float*)d_in[11];
  const float* s_b      = (const float*)d_in[12];
  const float* s_v      = (const float*)d_in[13];
  const float* gcn_w    = (const float*)d_in[14];
  const float* gcn_b    = (const float*)d_in[15];
  const float* time_w   = (const float*)d_in[16];
  const float* time_b   = (const float*)d_in[17];
  const float* ln_w     = (const float*)d_in[18];
  const float* ln_b     = (const float*)d_in[19];

  float* out  = (float*)d_out;
  float* Sout = out + S_OFF;
  float* Tout = out + T_OFF;
  u16*   outU = (u16*)d_out;
  float* ws   = (float*)d_ws;

  u16*   gcnB = (u16*)(ws + O_GCN);
  u16*   rawp = (u16*)(ws + O_GCN);      // alias: dead before gcnB written
  u16*   xTlc = (u16*)(ws + O_XTLC);
  u16*   xr   = (u16*)(ws + O_XR);
  u16*   z1   = (u16*)(ws + O_Z1);
  u16*   z2   = (u16*)(ws + O_Z2);
  float* f1t  = ws + O_F1T;
  float* f1s  = ws + O_F1S;
  float* f2t  = ws + O_F2T;
  float* f2s  = ws + O_F2S;
  float* g_t  = ws + O_GT;
  float* g_s  = ws + O_GS;
  float* cm   = ws + O_CM;
  u16*   WAp  = (u16*)(ws + O_WAP);
  u16*   W2p  = (u16*)(ws + O_W2P);
  float* part = ws + O_PART;
  float* bst  = ws + O_BST;

  u16*   A1p  = outU + OS_A1;
  u16*   A2p  = outU + OS_A2;
  u16*   Xp   = outU + OS_XP;
  u16*   svp  = outU + OS_SV;
  float* sup2 = (float*)(outU + OS_SUP2);

  constexpr long NN = (long)N_*N_;

  k_f1<<<1536, 256, 0, stream>>>(x, t1w, s1w, f1t, f1s);
  k_f2t<<<B_*C_, 768, 0, stream>>>(x, t2w, f2t);
  k_f2s<<<2048, 256, 0, stream>>>(x, s2w, f2s);
  k_gt<<<B_*L_, 1024, 0, stream>>>(f1t, t_w, g_t);
  k_gs<<<2048, 256, 0, stream>>>(f1s, s_w, g_s);
  k_tatt<<<B_, 576, 0, stream>>>(g_t, f2t, t_b, t_v, Tout);
  k_raws_pack<<<8192, 256, 0, stream>>>(g_s, f2s, s_b, rawp);
  k_pack_sv<<<512, 256, 0, stream>>>(s_v, svp);
  k_mm<1><<<dim3(16, 16, 1), 256, 0, stream>>>(supports, supports, sup2, N_, N_, N_, N_);
  // logits = s_v @ raw_s  (f32 out into d_out S region)
  k_mfma<0, 0><<<dim3(8, 8, B_), 256, 0, stream>>>(svp, svp, rawp, Sout, Sout,
                                                   N_, N_, 0, NN, NN);
  k_colmax<<<64, 256, 0, stream>>>(Sout, cm);
  k_softmax<<<B_*N_, 256, 0, stream>>>(Sout, cm);
  k_xtat<<<B_*N_, 768, 0, stream>>>(x, Tout, xTlc, xr);
  k_pack_cheb<<<8192, 256, 0, stream>>>(Sout, supports, sup2, A1p, A2p);
  k_pack_x<<<6144, 256, 0, stream>>>(xTlc, Xp);
  // z1,z2 bf16 (dual MFMA)
  k_mfma<1, 1><<<dim3(6, 8, B_), 256, 0, stream>>>(A1p, A2p, Xp, z1, z2,
                                                   N_, 768, NN, (long)N_*768, (long)N_*768);
  k_zpad<<<2048, 256, 0, stream>>>(gcnB);
  k_wpack<<<56, 256, 0, stream>>>(gcn_w, time_w, conv1_w, WAp, W2p);
  k_ga<<<3072, 256, 0, stream>>>(xTlc, z1, z2, Sout, WAp, gcn_b, gcnB);
  k_gb<<<3072, 256, 0, stream>>>(gcnB, xr, W2p, time_b, conv1_b, out, part);
  k_bstats<<<B_, 256, 0, stream>>>(part, bst);
  k_ln<<<98304, 256, 0, stream>>>(out, bst, ln_w, ln_b);
}

// Round 4
// 597.616 us; speedup vs baseline: 3.4479x; 1.2723x over previous
//
#include <hip/hip_runtime.h>
#include <cstddef>

namespace {
constexpr int B_ = 16, C_ = 32, N_ = 1024, L_ = 24, CO_ = 64;

constexpr size_t S_OFF = (size_t)B_*CO_*N_*L_;            // 25165824 floats
constexpr size_t T_OFF = S_OFF + (size_t)B_*N_*N_;        // 41943040

// ---- workspace layout (f32 units) ----
constexpr size_t O_GCN  = 0;                              // gcn bf16 [B][N][26][64] (rawp aliases first 16M u16)
constexpr size_t O_XTLC = 13631488;                       // xT bf16 [B][N][768] (l*32+c)
constexpr size_t O_XR   = 19922944;                       // x  bf16 [B][N][768] (l*32+c)
constexpr size_t O_Z1   = 26214400;                       // z1 bf16 [B][N][768]
constexpr size_t O_Z2   = 32505856;                       // z2 bf16
constexpr size_t O_F1T  = 38797312;
constexpr size_t O_F1S  = 39190528;
constexpr size_t O_F2T  = 39583744;
constexpr size_t O_F2S  = 39596032;
constexpr size_t O_GT   = 40120320;
constexpr size_t O_GS   = 40132608;
constexpr size_t O_CM   = 40656896;                       // colmax keys u32 [B][N]
constexpr size_t O_WAP  = 40673280;                       // GA weights packed (6144 u16)
constexpr size_t O_W2P  = 40676352;                       // GB weights packed (14336 u16)
constexpr size_t O_PART = 40683520;                       // [3072][2]
constexpr size_t O_BST  = 40689664;                       // [B][2]

// ---- d_out scratch (u16 units), region [0, S_OFF floats) dead until k_gb ----
constexpr size_t OS_A1  = 0;
constexpr size_t OS_A2  = OS_A1 + (size_t)B_*N_*N_;
constexpr size_t OS_XP  = OS_A2 + (size_t)B_*N_*N_;
constexpr size_t OS_SV  = OS_XP + (size_t)B_*N_*768;
constexpr size_t OS_SUP2= OS_SV + (size_t)N_*N_;          // sup2 f32 [N][N]

typedef unsigned short u16;
typedef __attribute__((ext_vector_type(8))) short short8v;
typedef __attribute__((ext_vector_type(4))) float f32x4;

__device__ __forceinline__ u16 f2bf(float x) {
  unsigned u = __builtin_bit_cast(unsigned, x);
  return (u16)((u + 0x7fffu + ((u >> 16) & 1u)) >> 16);
}
__device__ __forceinline__ float bf2f(u16 v) {
  return __builtin_bit_cast(float, ((unsigned)v) << 16);
}
// monotonic float<->unsigned key (order-preserving; max on keys == max on floats)
__device__ __forceinline__ unsigned fkey(float f) {
  unsigned u = __builtin_bit_cast(unsigned, f);
  return (u & 0x80000000u) ? ~u : (u | 0x80000000u);
}
__device__ __forceinline__ float funkey(unsigned k) {
  unsigned u = (k & 0x80000000u) ? (k ^ 0x80000000u) : ~k;
  return __builtin_bit_cast(float, u);
}
__device__ __forceinline__ void gl_lds16(const void* g, void* l) {
  __builtin_amdgcn_global_load_lds(
      (const __attribute__((address_space(1))) unsigned int*)g,
      (__attribute__((address_space(3))) unsigned int*)l, 16, 0, 0);
}

// ---------------- stage 1: fused channel reductions over x ----------------
__global__ void k_f1(const float* __restrict__ x, const float* __restrict__ t1w,
                     const float* __restrict__ s1w, float* __restrict__ f1t,
                     float* __restrict__ f1s) {
  int idx = blockIdx.x * 256 + threadIdx.x;          // B*N*L
  int b = idx / (N_*L_); int r = idx % (N_*L_); int n = r / L_; int l = r % L_;
  const float* xp = x + ((size_t)b*C_*N_ + n)*L_ + l;
  float a1 = 0.f, a2 = 0.f;
  #pragma unroll
  for (int c = 0; c < C_; c++) {
    float v = xp[(size_t)c*N_*L_];
    a1 += v * t1w[c]; a2 += v * s1w[c];
  }
  f1t[((size_t)b*L_ + l)*N_ + n] = a1;
  f1s[idx] = a2;
}

__global__ __launch_bounds__(768) void k_f2t(const float* __restrict__ x,
    const float* __restrict__ w, float* __restrict__ f2t) {
  int bc = blockIdx.x; int tid = threadIdx.x;
  int nsub = tid / 24, l = tid % 24;
  const float* xp = x + (size_t)bc*N_*L_;
  float a = 0.f;
  for (int i = 0; i < 32; i++) {
    int n = nsub + i*32;
    a += xp[(size_t)n*24 + l] * w[n];
  }
  __shared__ float s[768];
  s[tid] = a; __syncthreads();
  for (int off = 16; off >= 1; off >>= 1) {
    if (nsub < off) s[tid] += s[tid + off*24];
    __syncthreads();
  }
  if (tid < 24) f2t[(size_t)bc*24 + tid] = s[tid];
}

__global__ void k_f2s(const float* __restrict__ x, const float* __restrict__ w,
                      float* __restrict__ f2s) {
  int idx = blockIdx.x * 256 + threadIdx.x;          // B*C*N
  const float* xp = x + (size_t)idx * L_;
  float a = 0.f;
  #pragma unroll
  for (int l = 0; l < L_; l++) a += xp[l] * w[l];
  f2s[idx] = a;
}

__global__ __launch_bounds__(1024) void k_gt(const float* __restrict__ f1t,
    const float* __restrict__ tw, float* __restrict__ g_t) {
  int bl = blockIdx.x; int tid = threadIdx.x;
  int nsub = tid >> 5, c = tid & 31;
  const float* f = f1t + (size_t)bl * N_;
  float a = 0.f;
  for (int i = 0; i < 32; i++) {
    int n = nsub + (i << 5);
    a += f[n] * tw[n*32 + c];
  }
  __shared__ float s[1024];
  s[tid] = a; __syncthreads();
  for (int off = 512; off >= 32; off >>= 1) {
    if (tid < off) s[tid] += s[tid + off];
    __syncthreads();
  }
  if (tid < 32) g_t[(size_t)bl*32 + tid] = s[tid];
}

__global__ void k_gs(const float* __restrict__ f1s, const float* __restrict__ sw,
                     float* __restrict__ g_s) {
  int idx = blockIdx.x * 256 + threadIdx.x;          // B*N*C
  int bn = idx >> 5, c = idx & 31;
  const float* f = f1s + (size_t)bn * L_;
  float a = 0.f;
  #pragma unroll
  for (int l = 0; l < L_; l++) a += f[l] * sw[l*32 + c];
  g_s[idx] = a;
}

// ---------------- temporal attention ----------------
__global__ __launch_bounds__(576) void k_tatt(const float* __restrict__ g_t,
    const float* __restrict__ f2t, const float* __restrict__ tb,
    const float* __restrict__ tv, float* __restrict__ Tout) {
  int b = blockIdx.x; int tid = threadIdx.x;
  int l = tid / 24, q = tid % 24;
  __shared__ float rawS[576], logS[576], cmS[24], rmS[24], rsS[24];
  float acc = tb[tid];
  const float* g = g_t + ((size_t)b*L_ + l)*C_;
  const float* f = f2t + (size_t)b*C_*L_ + q;
  #pragma unroll
  for (int c = 0; c < C_; c++) acc += g[c] * f[(size_t)c*L_];
  rawS[tid] = 1.f / (1.f + expf(-acc));
  __syncthreads();
  float lg = 0.f;
  #pragma unroll
  for (int k = 0; k < L_; k++) lg += tv[l*L_ + k] * rawS[k*L_ + q];
  logS[tid] = lg;
  __syncthreads();
  if (l == 0) { float m = -3.4e38f; for (int mm = 0; mm < L_; mm++) m = fmaxf(m, logS[mm*L_ + q]); cmS[q] = m; }
  __syncthreads();
  float lc = lg - cmS[q];
  logS[tid] = lc;
  __syncthreads();
  if (q == 0) { float m = -3.4e38f; for (int qq = 0; qq < L_; qq++) m = fmaxf(m, logS[l*L_ + qq]); rmS[l] = m; }
  __syncthreads();
  float e = expf(lc - rmS[l]);
  logS[tid] = e;
  __syncthreads();
  if (q == 0) { float s = 0.f; for (int qq = 0; qq < L_; qq++) s += logS[l*L_ + qq]; rsS[l] = s; }
  __syncthreads();
  Tout[(size_t)b*576 + q*24 + l] = e / rsS[l];
}

// ---------------- raw_s sigmoid -> packed-B bf16 directly ----------------
__global__ void k_raws_pack(const float* __restrict__ g_s, const float* __restrict__ f2s,
                            const float* __restrict__ sb, u16* __restrict__ rawp) {
  int t = blockIdx.x * 256 + threadIdx.x;
  int b = t >> 17, tt = t & 131071;
  int fi = tt >> 6, l = tt & 63;
  int kb = fi >> 6, nb = fi & 63;
  int m  = (nb << 4) + (l & 15);
  int n0 = (kb << 5) + ((l >> 4) << 3);
  const float* f = f2s + ((size_t)b*C_*N_) + m;
  float fv[C_];
  #pragma unroll
  for (int c = 0; c < C_; c++) fv[c] = f[(size_t)c << 10];
  const float* g = g_s + (((size_t)b << 10) + n0) * C_;
  u16* d = rawp + ((size_t)b << 20) + ((size_t)fi << 9) + (l << 3);
  #pragma unroll
  for (int j = 0; j < 8; j++) {
    float a = sb[(size_t)(n0 + j)*N_ + m];
    const float* gr = g + j*C_;
    #pragma unroll
    for (int c = 0; c < C_; c++) a += gr[c] * fv[c];
    d[j] = f2bf(1.f / (1.f + expf(-a)));
  }
}

// ---------------- pack s_v (A layout) + GA/GB weight pack + colmax zero ----------------
__global__ void k_pack_sv(const float* __restrict__ sv, u16* __restrict__ svp,
                          const float* __restrict__ gcn_w, const float* __restrict__ time_w,
                          const float* __restrict__ conv1_w, u16* __restrict__ WAp,
                          u16* __restrict__ W2p, unsigned* __restrict__ cmz) {
  int t = blockIdx.x * 256 + threadIdx.x;            // 131072
  int fi = t >> 6, l = t & 63;
  int mg = fi >> 5, kg = fi & 31;
  int row = (mg << 4) + (l & 15);
  int k   = (kg << 5) + ((l >> 4) << 3);
  const float* s = sv + (size_t)row*N_ + k;
  u16* d = svp + ((size_t)fi << 9) + (l << 3);
  #pragma unroll
  for (int j = 0; j < 8; j++) d[j] = f2bf(s[j]);
  if (t < 16384) cmz[t] = 0u;
  if (t < 6144) {
    int fi2 = t >> 9, l2 = (t >> 3) & 63, j2 = t & 7;
    int kg2 = fi2 >> 2, cf = fi2 & 3;
    int o = cf*16 + (l2 & 15), c = ((l2 >> 4) << 3) + j2;
    WAp[t] = f2bf(gcn_w[o*96 + c*3 + kg2]);
  }
  if (t < 14336) {
    int fi2 = t >> 9, l2 = (t >> 3) & 63, j2 = t & 7;
    int kg2 = fi2 >> 2, cf = fi2 & 3;
    int o2 = cf*16 + (l2 & 15), kk = ((l2 >> 4) << 3) + j2;
    float v;
    if (kg2 < 6) { int tt = kg2 >> 1, i = (kg2 & 1)*32 + kk; v = time_w[o2*192 + i*3 + tt]; }
    else v = conv1_w[o2*32 + kk];
    W2p[t] = f2bf(v);
  }
}

// ---------------- pack A1=S.*sup, A2=S.*sup2 (+ gcn pad zero) ----------------
__global__ void k_pack_cheb(const float* __restrict__ S, const float* __restrict__ sup,
                            const float* __restrict__ sup2, u16* __restrict__ A1p,
                            u16* __restrict__ A2p, u16* __restrict__ gcnB) {
  int t = blockIdx.x * 256 + threadIdx.x;
  int b = t >> 17, tt = t & 131071;
  int fi = tt >> 6, l = tt & 63;
  int mg = fi >> 5, kg = fi & 31;
  int row = (mg << 4) + (l & 15);
  int k   = (kg << 5) + ((l >> 4) << 3);
  const float* sp = S + ((size_t)b << 20) + (size_t)row*N_ + k;
  const float* p1 = sup  + (size_t)row*N_ + k;
  const float* p2 = sup2 + (size_t)row*N_ + k;
  size_t off = ((size_t)b << 20) + ((size_t)fi << 9) + (l << 3);
  #pragma unroll
  for (int j = 0; j < 8; j++) {
    float s = sp[j];
    A1p[off + j] = f2bf(s * p1[j]);
    A2p[off + j] = f2bf(s * p2[j]);
  }
  if (t < 524288) {                                  // zero gcn l-pads (rawp alias dead here)
    int o4 = t & 15, rest = t >> 4;
    int half = rest & 1, bn = rest >> 1;
    size_t po = ((size_t)bn*26 + half*25)*64 + o4*4;
    *(unsigned long long*)&gcnB[po] = 0ull;
  }
}

// ---------------- pack xT into cheb B-operand ----------------
__global__ void k_pack_x(const u16* __restrict__ xTlc, u16* __restrict__ Xp) {
  int t = blockIdx.x * 256 + threadIdx.x;            // B * 98304
  int b = t / 98304, tt = t % 98304;
  int fi = tt >> 6, l = tt & 63;
  int kb = fi / 48, nb = fi % 48;
  int col = (nb << 4) + (l & 15);
  int kr  = (kb << 5) + ((l >> 4) << 3);
  const u16* xs = xTlc + ((size_t)b*N_ + kr)*768 + col;
  u16* d = Xp + (size_t)b*786432 + ((size_t)fi << 9) + (l << 3);
  #pragma unroll
  for (int j = 0; j < 8; j++) d[j] = xs[(size_t)j*768];
}

// ---------------- bf16 MFMA GEMM, 128x128 tile ----------------
// OUTBF: bf16 outputs. CMAX: fused per-column max (keys) into cmg.
template <int DUAL, int OUTBF, int CMAX>
__global__ __launch_bounds__(256) void k_mfma(
    const u16* __restrict__ Ap, const u16* __restrict__ A2p,
    const u16* __restrict__ Bp, void* __restrict__ D1, void* __restrict__ D2,
    unsigned* __restrict__ cmg, int Kd, int Ncols, long sA, long sB, long sD) {
  int b = blockIdx.z;
  const u16* A1 = Ap + (size_t)b * sA;
  const u16* A2 = DUAL ? (A2p + (size_t)b * sA) : nullptr;
  const u16* Bm = Bp + (size_t)b * sB;
  int mg0 = blockIdx.y * 8;
  int ng0 = blockIdx.x * 8;
  int Kg = Kd >> 5;
  int Ng = Ncols >> 4;
  int tid = threadIdx.x;
  int w = tid >> 6, lane = tid & 63;
  int wr = w >> 1, wc = w & 1;
  __shared__ __align__(16) u16 smem[(DUAL ? 3 : 2) * 8192];
  u16* As  = smem;
  u16* A2s = smem + 8192;
  u16* Bs  = smem + (DUAL ? 16384 : 8192);
  f32x4 acc1[4][4] = {};
  f32x4 acc2[4][4] = {};

  for (int k0 = 0; k0 < Kg; k0 += 2) {
    __syncthreads();
    #pragma unroll
    for (int i = 0; i < 4; i++) {
      int f = w + 4*i;
      int r = f >> 1, c = f & 1;
      size_t goff = (((size_t)(mg0 + r)) * Kg + (k0 + c)) * 512 + (lane << 3);
      gl_lds16(A1 + goff, &As[f * 512]);
      if (DUAL) gl_lds16(A2 + goff, &A2s[f * 512]);
      int cb = f >> 3, tn = f & 7;
      size_t boff = (((size_t)(k0 + cb)) * Ng + (ng0 + tn)) * 512 + (lane << 3);
      gl_lds16(Bm + boff, &Bs[f * 512]);
    }
    __syncthreads();
    #pragma unroll
    for (int kk = 0; kk < 2; kk++) {
      short8v bq[4], av[4], av2[4];
      #pragma unroll
      for (int j = 0; j < 4; j++)
        bq[j] = *(const short8v*)&Bs[(kk*8 + wc*4 + j)*512 + (lane << 3)];
      #pragma unroll
      for (int i = 0; i < 4; i++) {
        av[i] = *(const short8v*)&As[((wr*4 + i)*2 + kk)*512 + (lane << 3)];
        if (DUAL)
          av2[i] = *(const short8v*)&A2s[((wr*4 + i)*2 + kk)*512 + (lane << 3)];
      }
      #pragma unroll
      for (int i = 0; i < 4; i++)
        #pragma unroll
        for (int j = 0; j < 4; j++) {
          acc1[i][j] = __builtin_amdgcn_mfma_f32_16x16x32_bf16(av[i], bq[j], acc1[i][j], 0, 0, 0);
          if (DUAL)
            acc2[i][j] = __builtin_amdgcn_mfma_f32_16x16x32_bf16(av2[i], bq[j], acc2[i][j], 0, 0, 0);
        }
    }
  }
  if (CMAX) {
    // fused column-max: 128 cols per block; order-independent via monotone keys
    __shared__ unsigned cmL[128];
    if (tid < 128) cmL[tid] = 0u;
    __syncthreads();
    #pragma unroll
    for (int j = 0; j < 4; j++) {
      float m = -3.4e38f;
      #pragma unroll
      for (int i = 0; i < 4; i++)
        #pragma unroll
        for (int r = 0; r < 4; r++) m = fmaxf(m, acc1[i][j][r]);
      m = fmaxf(m, __shfl_xor(m, 16));
      m = fmaxf(m, __shfl_xor(m, 32));
      if ((lane >> 4) == 0)
        atomicMax(&cmL[wc*64 + j*16 + (lane & 15)], fkey(m));
    }
    __syncthreads();
    if (tid < 128)
      atomicMax(&cmg[(size_t)b*N_ + ng0*16 + tid], cmL[tid]);
  }
  #pragma unroll
  for (int i = 0; i < 4; i++) {
    int row = (mg0 + wr*4 + i)*16 + ((lane >> 4) << 2);
    #pragma unroll
    for (int j = 0; j < 4; j++) {
      int col = (ng0 + wc*4 + j)*16 + (lane & 15);
      #pragma unroll
      for (int r = 0; r < 4; r++) {
        size_t o = (size_t)(row + r)*Ncols + col;
        if (OUTBF) {
          ((u16*)D1)[(size_t)b*sD + o] = f2bf(acc1[i][j][r]);
          if (DUAL) ((u16*)D2)[(size_t)b*sD + o] = f2bf(acc2[i][j][r]);
        } else {
          ((float*)D1)[(size_t)b*sD + o] = acc1[i][j][r];
          if (DUAL) ((float*)D2)[(size_t)b*sD + o] = acc2[i][j][r];
        }
      }
    }
  }
}

// ---------------- f32 tiled GEMM (supports@supports only) ----------------
template <int MODE>
__global__ __launch_bounds__(256) void k_mm(const float* __restrict__ A,
    const float* __restrict__ Bm, float* __restrict__ D, int Kd,
    int ldA, int ldB, int ldD) {
  int n0 = blockIdx.x * 64, m0 = blockIdx.y * 64;
  int tid = threadIdx.x;
  int tx = tid & 15, ty = tid >> 4;
  __shared__ __align__(16) float As[16][68], Bs[16][68];
  float acc[4][4] = {};
  int arow = tid >> 2, akq = (tid & 3) * 4;
  int bkk = tid >> 4, bcol = (tid & 15) * 4;
  const float* Ap = A + (size_t)(m0 + arow)*ldA + akq;
  const float* Bp = Bm + (size_t)bkk*ldB + n0 + bcol;
  for (int k0 = 0; k0 < Kd; k0 += 16) {
    float4 a4 = *(const float4*)(Ap + k0);
    float4 b4 = *(const float4*)(Bp + (size_t)k0 * ldB);
    __syncthreads();
    As[akq+0][arow] = a4.x; As[akq+1][arow] = a4.y;
    As[akq+2][arow] = a4.z; As[akq+3][arow] = a4.w;
    *(float4*)&Bs[bkk][bcol] = b4;
    __syncthreads();
    #pragma unroll
    for (int kk = 0; kk < 16; kk++) {
      float av[4], bv[4];
      *(float4*)av = *(const float4*)&As[kk][ty*4];
      *(float4*)bv = *(const float4*)&Bs[kk][tx*4];
      #pragma unroll
      for (int i = 0; i < 4; i++)
        #pragma unroll
        for (int j = 0; j < 4; j++) acc[i][j] += av[i] * bv[j];
    }
  }
  #pragma unroll
  for (int i = 0; i < 4; i++) {
    int rr = m0 + ty*4 + i;
    float ov[4];
    #pragma unroll
    for (int j = 0; j < 4; j++) {
      float v = acc[i][j];
      if (MODE == 1) v = 2.f*v - ((rr == n0 + tx*4 + j) ? 1.f : 0.f);
      ov[j] = v;
    }
    *(float4*)&D[(size_t)rr*ldD + n0 + tx*4] = *(float4*)ov;
  }
}

// ---------------- in-place row softmax of (logits - colmax) ----------------
__global__ __launch_bounds__(256) void k_softmax(float* __restrict__ S,
                                                 const unsigned* __restrict__ cm) {
  int bm = blockIdx.x; int tid = threadIdx.x;
  int b = bm >> 10;
  float* row = S + (size_t)bm * N_;
  const unsigned* cmb = cm + (size_t)b * N_;
  float v[4]; float mx = -3.4e38f;
  #pragma unroll
  for (int j = 0; j < 4; j++) {
    int q = tid + j*256;
    v[j] = row[q] - funkey(cmb[q]);
    mx = fmaxf(mx, v[j]);
  }
  #pragma unroll
  for (int off = 32; off; off >>= 1) mx = fmaxf(mx, __shfl_down(mx, off));
  __shared__ float sm[4], ss[4];
  if ((tid & 63) == 0) sm[tid >> 6] = mx;
  __syncthreads();
  mx = fmaxf(fmaxf(sm[0], sm[1]), fmaxf(sm[2], sm[3]));
  float e[4]; float s = 0.f;
  #pragma unroll
  for (int j = 0; j < 4; j++) { e[j] = expf(v[j] - mx); s += e[j]; }
  #pragma unroll
  for (int off = 32; off; off >>= 1) s += __shfl_down(s, off);
  if ((tid & 63) == 0) ss[tid >> 6] = s;
  __syncthreads();
  float inv = 1.f / (ss[0] + ss[1] + ss[2] + ss[3]);
  #pragma unroll
  for (int j = 0; j < 4; j++) row[tid + j*256] = e[j] * inv;
}

// ---------------- x_TAt: bf16 (l*32+c) order, + x relayout ----------------
__global__ __launch_bounds__(768) void k_xtat(const float* __restrict__ x,
    const float* __restrict__ Tout, u16* __restrict__ xTlc, u16* __restrict__ xr) {
  int bn = blockIdx.x; int b = bn >> 10, n = bn & 1023;
  __shared__ float xrow[768], Tl[576];
  int tid = threadIdx.x;
  int c = tid / 24, q = tid % 24;
  float xv = x[(((size_t)b*C_ + c)*N_ + n)*L_ + q];
  xrow[tid] = xv;
  if (tid < 576) Tl[tid] = Tout[(size_t)b*576 + tid];
  xr[(size_t)bn*768 + q*32 + c] = f2bf(xv);
  __syncthreads();
  float acc = 0.f;
  #pragma unroll
  for (int ll = 0; ll < 24; ll++) acc += xrow[c*24 + ll] * Tl[ll*24 + q];
  xTlc[(size_t)bn*768 + q*32 + c] = f2bf(acc);
}

// ---------------- GA: gcn = relu(W[64x96] @ F), reg-only MFMA ----------------
__global__ __launch_bounds__(256) void k_ga(const u16* __restrict__ xTlc,
    const u16* __restrict__ z1, const u16* __restrict__ z2,
    const float* __restrict__ S, const u16* __restrict__ WAp,
    const float* __restrict__ gcn_b, u16* __restrict__ gcn) {
  int blk = blockIdx.x;                              // 3072 = B*192
  int b = blk / 192, mt = blk % 192;
  int tid = threadIdx.x, w = tid >> 6, lane = tid & 63;
  int lm = lane & 15, hi = lane >> 4;
  short8v Bf[3][4];
  #pragma unroll
  for (int kg = 0; kg < 3; kg++)
    #pragma unroll
    for (int cf = 0; cf < 4; cf++)
      Bf[kg][cf] = *(const short8v*)&WAp[(kg*4 + cf)*512 + lane*8];
  f32x4 acc[2][4] = {};
  #pragma unroll
  for (int rf = 0; rf < 2; rf++) {
    int row = mt*128 + (w*2 + rf)*16 + lm;
    size_t ba = (size_t)b*786432 + (size_t)row*32 + hi*8;
    short8v a0 = *(const short8v*)&xTlc[ba];
    short8v a1 = *(const short8v*)&z1[ba];
    short8v a2 = *(const short8v*)&z2[ba];
    int n = row / 24;
    float sd = S[((size_t)b << 20) + (size_t)n*1025];
    #pragma unroll
    for (int j = 0; j < 8; j++)
      a0[j] = (short)f2bf(bf2f((u16)a0[j]) * sd);
    #pragma unroll
    for (int cf = 0; cf < 4; cf++) {
      acc[rf][cf] = __builtin_amdgcn_mfma_f32_16x16x32_bf16(a0, Bf[0][cf], acc[rf][cf], 0, 0, 0);
      acc[rf][cf] = __builtin_amdgcn_mfma_f32_16x16x32_bf16(a1, Bf[1][cf], acc[rf][cf], 0, 0, 0);
      acc[rf][cf] = __builtin_amdgcn_mfma_f32_16x16x32_bf16(a2, Bf[2][cf], acc[rf][cf], 0, 0, 0);
    }
  }
  #pragma unroll
  for (int rf = 0; rf < 2; rf++) {
    int rbase = mt*128 + (w*2 + rf)*16 + hi*4;
    #pragma unroll
    for (int cf = 0; cf < 4; cf++) {
      int o = cf*16 + lm;
      float gb = gcn_b[o];
      #pragma unroll
      for (int r = 0; r < 4; r++) {
        int row = rbase + r;
        int n = row / 24, l = row - 24*n;
        gcn[(((size_t)b*1024 + n)*26 + l + 1)*64 + o] = f2bf(fmaxf(acc[rf][cf][r] + gb, 0.f));
      }
    }
  }
}

// ---------------- GB: pre = relu(timeW@G + conv1W@x + biases), + LN partials ----------------
__global__ __launch_bounds__(256) void k_gb(const u16* __restrict__ gcn,
    const u16* __restrict__ xr, const u16* __restrict__ W2p,
    const float* __restrict__ time_b, const float* __restrict__ conv1_b,
    float* __restrict__ out, float* __restrict__ partials) {
  int blk = blockIdx.x;                              // 3072
  int b = blk / 192, mt = blk % 192;
  int tid = threadIdx.x, w = tid >> 6, lane = tid & 63;
  int lm = lane & 15, hi = lane >> 4;
  f32x4 acc[2][4] = {};
  #pragma unroll
  for (int g = 0; g < 7; g++) {
    short8v Bf[4];
    #pragma unroll
    for (int cf = 0; cf < 4; cf++)
      Bf[cf] = *(const short8v*)&W2p[(g*4 + cf)*512 + lane*8];
    #pragma unroll
    for (int rf = 0; rf < 2; rf++) {
      int row = mt*128 + (w*2 + rf)*16 + lm;
      short8v a;
      if (g < 6) {
        int n = row / 24, l = row - 24*n;
        int ts = g >> 1, o0 = (g & 1)*32;
        a = *(const short8v*)&gcn[(((size_t)b*1024 + n)*26 + l + ts)*64 + o0 + hi*8];
      } else {
        a = *(const short8v*)&xr[(size_t)b*786432 + (size_t)row*32 + hi*8];
      }
      #pragma unroll
      for (int cf = 0; cf < 4; cf++)
        acc[rf][cf] = __builtin_amdgcn_mfma_f32_16x16x32_bf16(a, Bf[cf], acc[rf][cf], 0, 0, 0);
    }
  }
  float s1 = 0.f, s2 = 0.f;
  #pragma unroll
  for (int rf = 0; rf < 2; rf++) {
    int rbase = mt*128 + (w*2 + rf)*16 + hi*4;
    int n = rbase / 24, l0 = rbase - 24*n;
    #pragma unroll
    for (int cf = 0; cf < 4; cf++) {
      int o2 = cf*16 + lm;
      float bias = time_b[o2] + conv1_b[o2];
      float ov[4];
      #pragma unroll
      for (int r = 0; r < 4; r++) {
        float pre = fmaxf(acc[rf][cf][r] + bias, 0.f);
        s1 += pre; s2 += pre*pre; ov[r] = pre;
      }
      *(float4*)&out[(((size_t)b*64 + o2)*1024 + n)*24 + l0] = *(float4*)ov;
    }
  }
  #pragma unroll
  for (int off = 32; off; off >>= 1) { s1 += __shfl_down(s1, off); s2 += __shfl_down(s2, off); }
  __shared__ float red[8];
  if (lane == 0) { red[w*2] = s1; red[w*2 + 1] = s2; }
  __syncthreads();
  if (tid == 0) {
    float t1 = 0.f, t2 = 0.f;
    for (int ww = 0; ww < 4; ww++) { t1 += red[ww*2]; t2 += red[ww*2 + 1]; }
    partials[blk*2] = t1; partials[blk*2 + 1] = t2;
  }
}

__global__ __launch_bounds__(256) void k_bstats(const float* __restrict__ partials,
                                                float* __restrict__ bstats) {
  int b = blockIdx.x; int tid = threadIdx.x;
  __shared__ float r1[256], r2[256];
  r1[tid] = (tid < 192) ? partials[(b*192 + tid)*2] : 0.f;
  r2[tid] = (tid < 192) ? partials[(b*192 + tid)*2 + 1] : 0.f;
  __syncthreads();
  for (int off = 128; off; off >>= 1) {
    if (tid < off) { r1[tid] += r1[tid + off]; r2[tid] += r2[tid + off]; }
    __syncthreads();
  }
  if (tid == 0) { bstats[b*2] = r1[0]; bstats[b*2 + 1] = r2[0]; }
}

__global__ void k_ln(float* __restrict__ out, const float* __restrict__ bstats,
                     const float* __restrict__ lnw, const float* __restrict__ lnb) {
  size_t idx = (size_t)blockIdx.x * 256 + threadIdx.x;
  constexpr size_t PER = (size_t)CO_*N_*L_;
  int b = (int)(idx / PER); size_t r = idx % PER;
  float cnt = (float)PER;
  float mu = bstats[b*2] / cnt;
  float var = bstats[b*2 + 1] / cnt - mu*mu;
  float inv = rsqrtf(var + 1e-5f);
  out[idx] = (out[idx] - mu) * inv * lnw[r] + lnb[r];
}
} // namespace

extern "C" void kernel_launch(void* const* d_in, const int* in_sizes, int n_in,
                              void* d_out, int out_size, void* d_ws, size_t ws_size,
                              hipStream_t stream) {
  const float* x        = (const float*)d_in[0];
  const float* supports = (const float*)d_in[1];
  const float* conv1_w  = (const float*)d_in[2];
  const float* conv1_b  = (const float*)d_in[3];
  const float* t1w      = (const float*)d_in[4];
  const float* t2w      = (const float*)d_in[5];
  const float* t_w      = (const float*)d_in[6];
  const float* t_b      = (const float*)d_in[7];
  const float* t_v      = (const float*)d_in[8];
  const float* s1w      = (const float*)d_in[9];
  const float* s2w      = (const float*)d_in[10];
  const float* s_w      = (const float*)d_in[11];
  const float* s_b      = (const float*)d_in[12];
  const float* s_v      = (const float*)d_in[13];
  const float* gcn_w    = (const float*)d_in[14];
  const float* gcn_b    = (const float*)d_in[15];
  const float* time_w   = (const float*)d_in[16];
  const float* time_b   = (const float*)d_in[17];
  const float* ln_w     = (const float*)d_in[18];
  const float* ln_b     = (const float*)d_in[19];

  float* out  = (float*)d_out;
  float* Sout = out + S_OFF;
  float* Tout = out + T_OFF;
  u16*   outU = (u16*)d_out;
  float* ws   = (float*)d_ws;

  u16*   gcnB = (u16*)(ws + O_GCN);
  u16*   rawp = (u16*)(ws + O_GCN);      // alias: dead before gcnB written
  u16*   xTlc = (u16*)(ws + O_XTLC);
  u16*   xr   = (u16*)(ws + O_XR);
  u16*   z1   = (u16*)(ws + O_Z1);
  u16*   z2   = (u16*)(ws + O_Z2);
  float* f1t  = ws + O_F1T;
  float* f1s  = ws + O_F1S;
  float* f2t  = ws + O_F2T;
  float* f2s  = ws + O_F2S;
  float* g_t  = ws + O_GT;
  float* g_s  = ws + O_GS;
  unsigned* cm = (unsigned*)(ws + O_CM);
  u16*   WAp  = (u16*)(ws + O_WAP);
  u16*   W2p  = (u16*)(ws + O_W2P);
  float* part = ws + O_PART;
  float* bst  = ws + O_BST;

  u16*   A1p  = outU + OS_A1;
  u16*   A2p  = outU + OS_A2;
  u16*   Xp   = outU + OS_XP;
  u16*   svp  = outU + OS_SV;
  float* sup2 = (float*)(outU + OS_SUP2);

  constexpr long NN = (long)N_*N_;

  k_f1<<<1536, 256, 0, stream>>>(x, t1w, s1w, f1t, f1s);
  k_f2t<<<B_*C_, 768, 0, stream>>>(x, t2w, f2t);
  k_f2s<<<2048, 256, 0, stream>>>(x, s2w, f2s);
  k_gt<<<B_*L_, 1024, 0, stream>>>(f1t, t_w, g_t);
  k_gs<<<2048, 256, 0, stream>>>(f1s, s_w, g_s);
  k_tatt<<<B_, 576, 0, stream>>>(g_t, f2t, t_b, t_v, Tout);
  k_raws_pack<<<8192, 256, 0, stream>>>(g_s, f2s, s_b, rawp);
  k_pack_sv<<<512, 256, 0, stream>>>(s_v, svp, gcn_w, time_w, conv1_w, WAp, W2p, cm);
  k_mm<1><<<dim3(16, 16, 1), 256, 0, stream>>>(supports, supports, sup2, N_, N_, N_, N_);
  // logits = s_v @ raw_s  (f32 out into d_out S region, fused column-max)
  k_mfma<0, 0, 1><<<dim3(8, 8, B_), 256, 0, stream>>>(svp, svp, rawp, Sout, Sout,
                                                      cm, N_, N_, 0, NN, NN);
  k_softmax<<<B_*N_, 256, 0, stream>>>(Sout, cm);
  k_xtat<<<B_*N_, 768, 0, stream>>>(x, Tout, xTlc, xr);
  k_pack_cheb<<<8192, 256, 0, stream>>>(Sout, supports, sup2, A1p, A2p, gcnB);
  k_pack_x<<<6144, 256, 0, stream>>>(xTlc, Xp);
  // z1,z2 bf16 (dual MFMA)
  k_mfma<1, 1, 0><<<dim3(6, 8, B_), 256, 0, stream>>>(A1p, A2p, Xp, z1, z2,
                                                      nullptr, N_, 768, NN,
                                                      (long)N_*768, (long)N_*768);
  k_ga<<<3072, 256, 0, stream>>>(xTlc, z1, z2, Sout, WAp, gcn_b, gcnB);
  k_gb<<<3072, 256, 0, stream>>>(gcnB, xr, W2p, time_b, conv1_b, out, part);
  k_bstats<<<B_, 256, 0, stream>>>(part, bst);
  k_ln<<<98304, 256, 0, stream>>>(out, bst, ln_w, ln_b);
}